// Round 6
// baseline (25799.512 us; speedup 1.0000x reference)
//
#include <hip/hip_runtime.h>
#include <hip/hip_fp16.h>
#include <math.h>

// Problem constants
#define SB   64     // batch
#define SN   128    // seq len
#define SE   1024   // feature dim
#define SD   256    // hidden D
#define SD2  512    // 2D
#define SD3  768    // 3D
#define SIN  2048   // 4D+E
#define SNC  7
#define SBN  8192   // SB*SN
#define CS   8      // chunk steps (GK tile held in LDS, fp16)

// dynamic LDS layout (bytes) for step_chunk_k
#define L_HS   0        // ushort[128*256] swizzled H shadow   (65536)
#define L_GK   65536    // ushort[CS*1536] GK tile             (24576)
#define L_XH   90112    // ushort[CS*256]  X tile              (4096)
#define L_QH   94208    // ushort[CS*256]  Q tile              (4096)
#define L_ADJ  98304    // float[CS*128]   adjacency masks     (4096)
#define L_MH   102400   // ushort[256]     M fp16              (512)
#define L_LGP  102912   // float[256]      score partials      (1024)
#define L_WGT  103936   // float[128]                          (512)
#define L_S0   104448   // float[CS]                           (64)
#define L_WR   104512   // weight ring: 4 waves x 2 bufs x 6KB (49152)
#define SMEM_BYTES 153664

typedef _Float16 h2v __attribute__((ext_vector_type(2)));

__device__ __forceinline__ float wsum(float v){
#pragma unroll
  for (int o = 32; o; o >>= 1) v += __shfl_xor(v, o);
  return v;
}
__device__ __forceinline__ float sigm(float x){ return 1.f/(1.f + expf(-x)); }

__device__ __forceinline__ unsigned short f2h(float f){
  return __half_as_ushort(__float2half_rn(f));
}
__device__ __forceinline__ float h2f_(unsigned short u){
  return __half2float(__ushort_as_half(u));
}
__device__ __forceinline__ h2v u2h(unsigned u){
  union { unsigned u; h2v h; } c; c.u = u; return c.h;
}
// dot of 8 fp16 (uint4) with 8 packed fp16 (uint4), f32 accum
__device__ __forceinline__ float dot8d(uint4 w, uint4 m, float acc){
  acc = __builtin_amdgcn_fdot2(u2h(w.x), u2h(m.x), acc, false);
  acc = __builtin_amdgcn_fdot2(u2h(w.y), u2h(m.y), acc, false);
  acc = __builtin_amdgcn_fdot2(u2h(w.z), u2h(m.z), acc, false);
  acc = __builtin_amdgcn_fdot2(u2h(w.w), u2h(m.w), acc, false);
  return acc;
}
// async global->LDS 16B per lane: lds dest = uniform base + lane*16
__device__ __forceinline__ void gl16(const void* g, void* l){
  __builtin_amdgcn_global_load_lds(
      (const __attribute__((address_space(1))) unsigned int*)g,
      (__attribute__((address_space(3))) unsigned int*)l, 16, 0, 0);
}

// ---------------------------------------------------------------------------
// Generic fp32 GEMM: C[M,N] = A @ op(B) (+bias)(+acc)(+relu), batched via z.
// ---------------------------------------------------------------------------
template<bool BKMAJ, bool BIAS, bool RELU, bool ACC>
__global__ __launch_bounds__(256)
void gemm_k(const float* __restrict__ A, const float* __restrict__ Bm,
            const float* __restrict__ bias, float* __restrict__ C,
            int Nn, int K, int lda, int ldb, int ldc,
            long sA, long sB, long sC)
{
  __shared__ float As[16][132];
  __shared__ float Bs[16][68];
  const int t  = threadIdx.x;
  const int tx = t & 15, ty = t >> 4;
  const float* Ab = A + (long)blockIdx.z * sA;
  const float* Bb = Bm + (long)blockIdx.z * sB;
  float* Cb = C + (long)blockIdx.z * sC;
  const int m0 = blockIdx.y * 128, n0 = blockIdx.x * 64;
  float acc[8][4];
#pragma unroll
  for (int i = 0; i < 8; ++i)
#pragma unroll
    for (int j = 0; j < 4; ++j) acc[i][j] = 0.f;

  const int am = t >> 1, ak = (t & 1) * 8;
  int bn_ = 0, bk_ = 0;
  if (BKMAJ) { bk_ = t >> 4; bn_ = (t & 15) * 4; }
  else       { bn_ = t >> 2; bk_ = (t & 3) * 4; }

  for (int k0 = 0; k0 < K; k0 += 16) {
    const float4 a0 = *(const float4*)(Ab + (long)(m0 + am) * lda + k0 + ak);
    const float4 a1 = *(const float4*)(Ab + (long)(m0 + am) * lda + k0 + ak + 4);
    float4 b0;
    if (BKMAJ) b0 = *(const float4*)(Bb + (long)(k0 + bk_) * ldb + n0 + bn_);
    else       b0 = *(const float4*)(Bb + (long)(n0 + bn_) * ldb + k0 + bk_);
    __syncthreads();
    As[ak+0][am] = a0.x; As[ak+1][am] = a0.y; As[ak+2][am] = a0.z; As[ak+3][am] = a0.w;
    As[ak+4][am] = a1.x; As[ak+5][am] = a1.y; As[ak+6][am] = a1.z; As[ak+7][am] = a1.w;
    if (BKMAJ) { *(float4*)&Bs[bk_][bn_] = b0; }
    else { Bs[bk_+0][bn_] = b0.x; Bs[bk_+1][bn_] = b0.y; Bs[bk_+2][bn_] = b0.z; Bs[bk_+3][bn_] = b0.w; }
    __syncthreads();
#pragma unroll
    for (int kk = 0; kk < 16; ++kk) {
      float av[8], bv[4];
      *(float4*)&av[0] = *(const float4*)&As[kk][ty*8];
      *(float4*)&av[4] = *(const float4*)&As[kk][ty*8+4];
      *(float4*)&bv[0] = *(const float4*)&Bs[kk][tx*4];
#pragma unroll
      for (int ii = 0; ii < 8; ++ii)
#pragma unroll
        for (int jj = 0; jj < 4; ++jj)
          acc[ii][jj] = fmaf(av[ii], bv[jj], acc[ii][jj]);
    }
  }
#pragma unroll
  for (int ii = 0; ii < 8; ++ii) {
#pragma unroll
    for (int jj = 0; jj < 4; ++jj) {
      float v = acc[ii][jj];
      if (BIAS) v += bias[n0 + tx*4 + jj];
      const long ci = (long)(m0 + ty*8 + ii) * ldc + n0 + tx*4 + jj;
      if (ACC) v += Cb[ci];
      if (RELU) v = fmaxf(v, 0.f);
      Cb[ci] = v;
    }
  }
}

// Htmp is b-major (row b*128+n). Write time-major X0f[(n*64+b)] and reversed.
__global__ void spread_k(const float* __restrict__ src, float* __restrict__ xf,
                         float* __restrict__ xr)
{
  const int r = blockIdx.x, t = threadIdx.x;   // src row = b*128+n
  const int b = r >> 7, n = r & 127;
  const float v = src[(long)r * SD + t];
  xf[((long)(n * 64 + b)) * SD + t] = v;
  xr[((long)((127 - n) * 64 + b)) * SD + t] = v;
}

// Pack transposed fp16 weights: Wt[cd][kb8][row][8] = fp16(W[row][kb8*8+q]),
// rows 0..767 from wc, 768..1535 from wp.  Grid (32 kb8, 4 cd).
struct PTArgs { const float* wc[4]; const float* wp[4]; unsigned short* Wt; };
__global__ void packT_k(PTArgs a)
{
  const int kb8 = blockIdx.x, cd = blockIdx.y, t = threadIdx.x;
#pragma unroll
  for (int p = 0; p < 6; ++p) {
    const int r = t + 256 * p;
    const float* src = (r < 768) ? (a.wc[cd] + (long)r * SD)
                                 : (a.wp[cd] + (long)(r - 768) * SD);
    const float4 v0 = *(const float4*)(src + kb8 * 8);
    const float4 v1 = *(const float4*)(src + kb8 * 8 + 4);
    uint4 o;
    o.x = (unsigned)f2h(v0.x) | ((unsigned)f2h(v0.y) << 16);
    o.y = (unsigned)f2h(v0.z) | ((unsigned)f2h(v0.w) << 16);
    o.z = (unsigned)f2h(v1.x) | ((unsigned)f2h(v1.y) << 16);
    o.w = (unsigned)f2h(v1.z) | ((unsigned)f2h(v1.w) << 16);
    *(uint4*)(a.Wt + (((size_t)cd * 32 + kb8) * 1536 + r) * 8) = o;
  }
}

// S0[m] = Q[m,:] . bk
__global__ void s0_k(const float* __restrict__ Q, const float* __restrict__ bk,
                     float* __restrict__ S0)
{
  const int r = blockIdx.x * 4 + (threadIdx.x >> 6), lane = threadIdx.x & 63;
  const float4 q  = *(const float4*)(Q + (long)r * SD + lane * 4);
  const float4 kb = *(const float4*)(bk + lane * 4);
  float p = q.x*kb.x + q.y*kb.y + q.z*kb.z + q.w*kb.w;
  p = wsum(p);
  if (lane == 0) S0[r] = p;
}

// ---------------------------------------------------------------------------
// Chunk step kernel: CS sequential DAG steps per launch (chunked relaunch
// keeps 64 blocks/cd phase-locked -> weight stream stays L2-resident).
// NEW: D-phase streams gate weights via global_load_lds into a PER-WAVE
// 2-deep LDS ring (wave w loads only rows {g*256 + w*64 .. +64} its lanes
// consume -> wave-private, NO barriers in D loop; counted vmcnt(6) keeps
// 12 loads in flight; lgkmcnt(0) guards the buffer-reuse WAR hazard).
// ---------------------------------------------------------------------------
struct StepArgs {
  const float* Qt[4]; const float* S0[4];
  const int* adj[4]; int rev[4];
  const float* bc[4];  const float* bp[4];   // cbhh, pbih (step-gate biases)
  const float* bgc[4]; const float* bgp[4];  // cbih, pbhh (GK biases)
  const float* X[4];
  float* H1[4];                              // time-major stride SD2, col-offset baked
  unsigned short* Hh;                        // fp16 shadow [cd*64+b][128][256] (LINEAR)
  const unsigned short* Wt;   // fp16 [cd][32][1536][8]: rows 0..767 cwhh, 768..1535 pwih
  const unsigned short* Wgk;  // fp16 [cd][32][1536][8]: rows 0..767 cwih, 768..1535 pwhh
  int ldX, s0;
};
__global__ __launch_bounds__(256, 1) void step_chunk_k(StepArgs a)
{
  extern __shared__ __align__(16) char dsm[];
  unsigned short* Hs  = (unsigned short*)(dsm + L_HS);   // swizzled
  unsigned short* GKh = (unsigned short*)(dsm + L_GK);
  unsigned short* Xh  = (unsigned short*)(dsm + L_XH);
  unsigned short* Qh  = (unsigned short*)(dsm + L_QH);
  float* adjc = (float*)(dsm + L_ADJ);
  unsigned short* Mh  = (unsigned short*)(dsm + L_MH);
  float* lgp  = (float*)(dsm + L_LGP);
  float* wgt  = (float*)(dsm + L_WGT);
  float* s0s  = (float*)(dsm + L_S0);

  const int blk = blockIdx.x;
  const int cd = blk & 3, b = blk >> 2;
  const int t = threadIdx.x, j = t;       // output column 0..255
  const int ldX = a.ldX, c0 = a.s0;
  const float* Xp  = a.X[cd];
  float* H1 = a.H1[cd];
  unsigned short* Hg = a.Hh + ((size_t)(cd * 64 + b)) * 128 * 256;  // linear
  const float* Qtp = a.Qt[cd];
  const float* S0p = a.S0[cd];
  const int*   adjp = a.adj[cd];
  const int    rev  = a.rev[cd];

  // hoisted biases for this thread's column j
  const float bc0 = a.bc[cd][j],  bc1 = a.bc[cd][256+j],  bc2 = a.bc[cd][512+j];
  const float bp0 = a.bp[cd][j],  bp1 = a.bp[cd][256+j],  bp2 = a.bp[cd][512+j];

  // ring bases: per-wave, per-lane gate-weight source
  char* ringb = dsm + L_WR + (size_t)(t >> 6) * 12288;
  const char* gw = (const char*)a.Wt + (size_t)cd * 786432 + (size_t)j * 16;
#define ISSUE_TILE(k, bb) { \
  const char* gt_ = gw + (size_t)(k) * 24576; \
  char* lb_ = ringb + (bb) * 6144; \
  gl16(gt_,          lb_); \
  gl16(gt_ + 4096,   lb_ + 1024); \
  gl16(gt_ + 8192,   lb_ + 2048); \
  gl16(gt_ + 12288,  lb_ + 3072); \
  gl16(gt_ + 16384,  lb_ + 4096); \
  gl16(gt_ + 20480,  lb_ + 5120); }

  // ---- prologue: stage X, Q (fp16), adjacency, S0; refill swizzled Hs ----
#pragma unroll
  for (int s = 0; s < CS; ++s) {
    Xh[s*256 + t] = f2h(Xp[((long)(c0+s)*64 + b)*ldX + t]);
    Qh[s*256 + t] = f2h(Qtp[((long)(c0+s)*64 + b)*SD + t]);
  }
  for (int z = t; z < CS*128; z += 256) {
    const int s = z >> 7, n = z & 127;
    const int i = c0 + s;
    int av = 0;
    if (i > 0) {
      const int ii = rev ? (SN-1-i) : i;
      const int nn = rev ? (SN-1-n) : n;
      av = adjp[((long)b*SN + ii)*SN + nn];
    }
    adjc[z] = (float)av;
  }
  if (t < CS) s0s[t] = S0p[(c0+t)*64 + b];
  for (int o = t*16; o < c0*512; o += 4096) {
    const uint4 v = *(const uint4*)((const char*)Hg + o);
    const int row = o >> 9, d2 = o & 511;
    *(uint4*)((char*)Hs + row*512 + (d2 ^ ((row & 31) << 4))) = v;
  }
  __syncthreads();

  // ---- GK phase (1-deep prefetch): GKh[s][g*256+j] = X[s].Wgk_row + bias ----
  {
    float gacc[6][CS];
#pragma unroll
    for (int g = 0; g < 6; ++g)
#pragma unroll
      for (int s = 0; s < CS; ++s) gacc[g][s] = 0.f;
    const unsigned short* wbgk = a.Wgk + ((size_t)cd*32*1536 + j)*8;
    uint4 wA[6], wB[6];
#pragma unroll
    for (int g = 0; g < 6; ++g) {
      wA[g] = ((const uint4*)wbgk)[g*256];
      wB[g] = ((const uint4*)(wbgk + 12288))[g*256];
    }
    for (int kb8 = 0; kb8 < 32; kb8 += 2) {
#pragma unroll
      for (int s = 0; s < CS; ++s) {
        const uint4 x8 = *(const uint4*)&Xh[s*256 + kb8*8];
#pragma unroll
        for (int g = 0; g < 6; ++g) gacc[g][s] = dot8d(wA[g], x8, gacc[g][s]);
      }
      if (kb8 + 2 < 32) {
        const uint4* wr = (const uint4*)(wbgk + (size_t)(kb8+2)*12288);
#pragma unroll
        for (int g = 0; g < 6; ++g) wA[g] = wr[g*256];
      }
#pragma unroll
      for (int s = 0; s < CS; ++s) {
        const uint4 x8 = *(const uint4*)&Xh[s*256 + kb8*8 + 8];
#pragma unroll
        for (int g = 0; g < 6; ++g) gacc[g][s] = dot8d(wB[g], x8, gacc[g][s]);
      }
      if (kb8 + 3 < 32) {
        const uint4* wr = (const uint4*)(wbgk + (size_t)(kb8+3)*12288);
#pragma unroll
        for (int g = 0; g < 6; ++g) wB[g] = wr[g*256];
      }
    }
#pragma unroll
    for (int g = 0; g < 6; ++g) {
      const float bg = (g < 3) ? a.bgc[cd][g*256 + j] : a.bgp[cd][(g-3)*256 + j];
#pragma unroll
      for (int s = 0; s < CS; ++s)
        GKh[s*1536 + g*256 + j] = f2h(gacc[g][s] + bg);
    }
  }
  __syncthreads();

  // ---- CS sequential steps ----
  for (int s = 0; s < CS; ++s) {
    const int i = c0 + s;
    const float xj = Xp[((long)i*64 + b)*ldX + j];
    float mreg = 0.f;
    if (i > 0) {
      // A: score — 2 threads/row, 16 kb8 each, swizzled LDS (2-way, free)
      {
        const int n = t & 127, hi = t >> 7;
        if (n < i) {
          const char* hrow = (const char*)Hs + n*512;
          const int cx = (n & 31) << 4;
          const unsigned short* qrow = Qh + s*256 + hi*128;
          float acc = 0.f;
#pragma unroll
          for (int k = 0; k < 16; ++k) {
            const uint4 hv = *(const uint4*)(hrow + (((hi*16 + k)*16) ^ cx));
            const uint4 qv = *(const uint4*)(qrow + k*8);
            acc = dot8d(hv, qv, acc);
          }
          lgp[t] = acc;
        }
      }
      __syncthreads();
      // B: softmax (wave 0)
      if (t < 64) {
        const float s0v = s0s[s];
        const int l = t;
        const float lg0 = lgp[l]      + lgp[128 + l];
        const float lg1 = lgp[64 + l] + lgp[192 + l];
        const float v0 = (l < i)    ? (lg0 + s0v - (1.f - adjc[s*128+l]   )*1e30f) : -3.0e38f;
        const float v1 = (l+64 < i) ? (lg1 + s0v - (1.f - adjc[s*128+l+64])*1e30f) : -3.0e38f;
        float mx = fmaxf(v0, v1);
#pragma unroll
        for (int o = 32; o; o >>= 1) mx = fmaxf(mx, __shfl_xor(mx, o));
        const float e0 = (l < i)    ? expf(v0 - mx) : 0.f;
        const float e1 = (l+64 < i) ? expf(v1 - mx) : 0.f;
        float sum = e0 + e1;
#pragma unroll
        for (int o = 32; o; o >>= 1) sum += __shfl_xor(sum, o);
        const float inv = 1.f / sum;
        if (l < i)    wgt[l]    = e0 * inv;
        if (l+64 < i) wgt[l+64] = e1 * inv;
      }
      __syncthreads();
    } else {
      Mh[t] = 0;
      __syncthreads();
    }

    // ring prologue: issue tiles 0,1 now; the C-phase + its barrier (which
    // drains vmcnt) give them the whole M phase to land.
    asm volatile("s_waitcnt vmcnt(0)" ::: "memory");
    ISSUE_TILE(0, 0);
    ISSUE_TILE(1, 1);

    if (i > 0) {
      // C: M — per-thread column j from swizzled LDS, 4 accumulator chains
      float m0 = 0.f, m1 = 0.f, m2 = 0.f, m3 = 0.f;
      int n = 0;
      for (; n + 4 <= i; n += 4) {
        m0 = fmaf(wgt[n+0], h2f_(Hs[(n+0)*256 + (j ^ (((n+0)&31)<<3))]), m0);
        m1 = fmaf(wgt[n+1], h2f_(Hs[(n+1)*256 + (j ^ (((n+1)&31)<<3))]), m1);
        m2 = fmaf(wgt[n+2], h2f_(Hs[(n+2)*256 + (j ^ (((n+2)&31)<<3))]), m2);
        m3 = fmaf(wgt[n+3], h2f_(Hs[(n+3)*256 + (j ^ (((n+3)&31)<<3))]), m3);
      }
      for (; n < i; ++n)
        m0 = fmaf(wgt[n], h2f_(Hs[n*256 + (j ^ ((n&31)<<3))]), m0);
      mreg = (m0 + m1) + (m2 + m3);
      Mh[t] = f2h(mreg);
    }
    __syncthreads();

    // D: gates — per-wave 2-deep LDS ring, counted vmcnt, no barriers
    float g0 = 0.f, g1 = 0.f, g2 = 0.f, g3 = 0.f, g4 = 0.f, g5 = 0.f;
    const int lo = (t & 63) * 16;
#pragma unroll 2
    for (int k = 0; k < 31; ++k) {
      asm volatile("s_waitcnt vmcnt(6)" ::: "memory");
      const char* buf = ringb + (k & 1) * 6144;
      const uint4 w0 = *(const uint4*)(buf + lo);
      const uint4 w1 = *(const uint4*)(buf + 1024 + lo);
      const uint4 w2 = *(const uint4*)(buf + 2048 + lo);
      const uint4 w3 = *(const uint4*)(buf + 3072 + lo);
      const uint4 w4 = *(const uint4*)(buf + 4096 + lo);
      const uint4 w5 = *(const uint4*)(buf + 5120 + lo);
      const uint4 m8 = *(const uint4*)&Mh[k*8];
      asm volatile("s_waitcnt lgkmcnt(0)" ::: "memory");  // reads done before overwrite
      if (k < 30) ISSUE_TILE(k + 2, (k & 1));
      g0 = dot8d(w0, m8, g0); g1 = dot8d(w1, m8, g1);
      g2 = dot8d(w2, m8, g2); g3 = dot8d(w3, m8, g3);
      g4 = dot8d(w4, m8, g4); g5 = dot8d(w5, m8, g5);
    }
    {
      asm volatile("s_waitcnt vmcnt(0)" ::: "memory");
      const char* buf = ringb + 6144;   // tile 31 -> buf 1
      const uint4 w0 = *(const uint4*)(buf + lo);
      const uint4 w1 = *(const uint4*)(buf + 1024 + lo);
      const uint4 w2 = *(const uint4*)(buf + 2048 + lo);
      const uint4 w3 = *(const uint4*)(buf + 3072 + lo);
      const uint4 w4 = *(const uint4*)(buf + 4096 + lo);
      const uint4 w5 = *(const uint4*)(buf + 5120 + lo);
      const uint4 m8 = *(const uint4*)&Mh[248];
      g0 = dot8d(w0, m8, g0); g1 = dot8d(w1, m8, g1);
      g2 = dot8d(w2, m8, g2); g3 = dot8d(w3, m8, g3);
      g4 = dot8d(w4, m8, g4); g5 = dot8d(w5, m8, g5);
    }

    // E: GRU elementwise + H1 row write (fp32) + fp16 shadows (LDS + global)
    {
      const int sb = s*1536;
      const float gic_r = h2f_(GKh[sb + j]);
      const float gic_z = h2f_(GKh[sb + 256 + j]);
      const float gic_n = h2f_(GKh[sb + 512 + j]);
      const float ghp_r = h2f_(GKh[sb + 768 + j]);
      const float ghp_z = h2f_(GKh[sb + 1024 + j]);
      const float ghp_n = h2f_(GKh[sb + 1280 + j]);
      const float rC = sigm(gic_r + g0 + bc0);
      const float zC = sigm(gic_z + g1 + bc1);
      const float nC = tanhf(gic_n + rC * (g2 + bc2));
      const float Cc = (1.f - zC) * nC + zC * mreg;
      const float rP = sigm(g3 + bp0 + ghp_r);
      const float zP = sigm(g4 + bp1 + ghp_z);
      const float nP = tanhf(g5 + bp2 + rP * ghp_n);
      const float hval = Cc + (1.f - zP) * nP + zP * xj;
      H1[((long)i*64 + b)*SD2 + j] = hval;
      const unsigned short hh = f2h(hval);
      Hs[i*256 + (j ^ ((i & 31) << 3))] = hh;   // swizzled LDS
      Hg[(size_t)i*256 + j] = hh;               // linear global (next chunk)
    }
    __syncthreads();
  }
#undef ISSUE_TILE
}

__global__ void zero_k(float* p, long n)
{
  for (long idx = (long)blockIdx.x * 256 + threadIdx.x; idx < n; idx += (long)gridDim.x * 256)
    p[idx] = 0.f;
}

// column means of (8192 x 512), grid (8 colblocks, 32 rowslices), atomicAdd
__global__ void colmean_k(const float* __restrict__ X, float* __restrict__ mean)
{
  __shared__ float red[256];
  const int c = blockIdx.x * 64 + (threadIdx.x & 63), rq = threadIdx.x >> 6;
  const int r0 = blockIdx.y * 256;
  float acc = 0.f;
  for (int r = r0 + rq; r < r0 + 256; r += 4) acc += X[(long)r * SD2 + c];
  red[threadIdx.x] = acc;
  __syncthreads();
  if (threadIdx.x < 64) {
    const float s = red[threadIdx.x] + red[64 + threadIdx.x] + red[128 + threadIdx.x] + red[192 + threadIdx.x];
    atomicAdd(&mean[c], s * (1.f / 8192.f));
  }
}

__global__ void rownorm_k(const float* __restrict__ X, const float* __restrict__ mean,
                          float* __restrict__ inv)
{
  const int r = blockIdx.x * 4 + (threadIdx.x >> 6), lane = threadIdx.x & 63;
  const float* xp = X + (long)r * SD2 + lane * 8;
  const float4 v0 = *(const float4*)xp;
  const float4 v1 = *(const float4*)(xp + 4);
  const float4 m0 = *(const float4*)(mean + lane * 8);
  const float4 m1 = *(const float4*)(mean + lane * 8 + 4);
  float ss = 0.f, d;
  d = v0.x - m0.x; ss += d*d;  d = v0.y - m0.y; ss += d*d;
  d = v0.z - m0.z; ss += d*d;  d = v0.w - m0.w; ss += d*d;
  d = v1.x - m1.x; ss += d*d;  d = v1.y - m1.y; ss += d*d;
  d = v1.z - m1.z; ss += d*d;  d = v1.w - m1.w; ss += d*d;
  ss = wsum(ss);
  if (lane == 0) inv[r] = 1.f / (sqrtf(ss) + 1e-6f);
}

// partial G += xhat^T yhat over K slice; grid (8, 8, 16)
__global__ __launch_bounds__(256)
void gpart_k(const float* __restrict__ X, const float* __restrict__ Y,
             const float* __restrict__ mx, const float* __restrict__ my,
             const float* __restrict__ ix, const float* __restrict__ iy,
             float* __restrict__ G)
{
  __shared__ float As[16][68];
  __shared__ float Bs[16][68];
  __shared__ float mxs[64], mys[64];
  const int t = threadIdx.x, tx = t & 15, ty = t >> 4;
  const int ci = blockIdx.y * 64, cj = blockIdx.x * 64;
  if (t < 64) { mxs[t] = mx[ci + t]; mys[t] = my[cj + t]; }
  float acc[4][4];
#pragma unroll
  for (int ii = 0; ii < 4; ++ii)
#pragma unroll
    for (int jj = 0; jj < 4; ++jj) acc[ii][jj] = 0.f;
  const int rl = t >> 4, c4 = (t & 15) * 4;
  __syncthreads();
  const int kend = blockIdx.z * 512 + 512;
  for (int kb = blockIdx.z * 512; kb < kend; kb += 16) {
    const int r = kb + rl;
    const float4 xv = *(const float4*)(X + (long)r * SD2 + ci + c4);
    const float4 yv = *(const float4*)(Y + (long)r * SD2 + cj + c4);
    const float vx = ix[r], vy = iy[r];
    __syncthreads();
    As[rl][c4+0] = (xv.x - mxs[c4+0]) * vx; As[rl][c4+1] = (xv.y - mxs[c4+1]) * vx;
    As[rl][c4+2] = (xv.z - mxs[c4+2]) * vx; As[rl][c4+3] = (xv.w - mxs[c4+3]) * vx;
    Bs[rl][c4+0] = (yv.x - mys[c4+0]) * vy; Bs[rl][c4+1] = (yv.y - mys[c4+1]) * vy;
    Bs[rl][c4+2] = (yv.z - mys[c4+2]) * vy; Bs[rl][c4+3] = (yv.w - mys[c4+3]) * vy;
    __syncthreads();
#pragma unroll
    for (int kk = 0; kk < 16; ++kk) {
      float av[4], bv[4];
      *(float4*)&av[0] = *(const float4*)&As[kk][ty*4];
      *(float4*)&bv[0] = *(const float4*)&Bs[kk][tx*4];
#pragma unroll
      for (int ii = 0; ii < 4; ++ii)
#pragma unroll
        for (int jj = 0; jj < 4; ++jj)
          acc[ii][jj] = fmaf(av[ii], bv[jj], acc[ii][jj]);
    }
  }
#pragma unroll
  for (int ii = 0; ii < 4; ++ii)
#pragma unroll
    for (int jj = 0; jj < 4; ++jj)
      atomicAdd(&G[(long)(ci + ty*4 + ii) * SD2 + cj + tx*4 + jj], acc[ii][jj]);
}

__global__ void sqsum_k(const float* __restrict__ G, float* __restrict__ dl)
{
  __shared__ float red[4];
  float s = 0.f;
  const long base = (long)blockIdx.x * 1024;
#pragma unroll
  for (int it = 0; it < 4; ++it) { const float v = G[base + it*256 + threadIdx.x]; s += v*v; }
  s = wsum(s);
  const int lane = threadIdx.x & 63, wv = threadIdx.x >> 6;
  if (lane == 0) red[wv] = s;
  __syncthreads();
  if (threadIdx.x == 0) atomicAdd(dl, red[0] + red[1] + red[2] + red[3]);
}

// softmax over rows of length 128 (in-place)
__global__ void smax_k(float* __restrict__ S)
{
  const int r = blockIdx.x * 4 + (threadIdx.x >> 6), lane = threadIdx.x & 63;
  float* p = S + (long)r * SN;
  const float v0 = p[lane], v1 = p[lane + 64];
  float mx = fmaxf(v0, v1);
#pragma unroll
  for (int o = 32; o; o >>= 1) mx = fmaxf(mx, __shfl_xor(mx, o));
  const float e0 = expf(v0 - mx), e1 = expf(v1 - mx);
  float s = e0 + e1;
#pragma unroll
  for (int o = 32; o; o >>= 1) s += __shfl_xor(s, o);
  const float inv = 1.f / s;
  p[lane] = e0 * inv; p[lane + 64] = e1 * inv;
}

__global__ void head_k(const float* __restrict__ H, const float* __restrict__ W,
                       const float* __restrict__ bo, float* __restrict__ out)
{
  const int r = blockIdx.x * 4 + (threadIdx.x >> 6), lane = threadIdx.x & 63;
  const float4 h = *(const float4*)(H + (long)r * SD + lane * 4);
#pragma unroll
  for (int c = 0; c < SNC; ++c) {
    const float4 w = *(const float4*)(W + (long)c * SD + lane * 4);
    float p = h.x*w.x + h.y*w.y + h.z*w.z + h.w*w.w;
    p = wsum(p);
    if (lane == 0) out[(long)r * SNC + c] = p + bo[c];
  }
}

__global__ void fin_k(const float* __restrict__ dl, float* __restrict__ out)
{
  out[0] = (dl[0] + dl[1]) * (0.3f / (512.f * 512.f));
}

// ---------------------------------------------------------------------------
extern "C" void kernel_launch(void* const* d_in, const int* in_sizes, int n_in,
                              void* d_out, int out_size, void* d_ws, size_t ws_size,
                              hipStream_t stream)
{
  (void)in_sizes; (void)n_in; (void)out_size; (void)ws_size;

  static bool attr_set = false;
  if (!attr_set) {
    hipFuncSetAttribute(reinterpret_cast<const void*>(step_chunk_k),
                        hipFuncAttributeMaxDynamicSharedMemorySize, SMEM_BYTES);
    attr_set = true;
  }

  const float* F    = (const float*)d_in[0];
  const int*   adj1 = (const int*)  d_in[1];
  const int*   adj2 = (const int*)  d_in[2];
  const float* fc1w = (const float*)d_in[6];
  const float* fc1b = (const float*)d_in[7];
  const float *g_wih[4], *g_whh[4], *g_bih[4], *g_bhh[4];  // gcs, gps, gcl, gpl
  for (int g = 0; g < 4; ++g) {
    g_wih[g] = (const float*)d_in[8 + g*4 + 0];
    g_whh[g] = (const float*)d_in[8 + g*4 + 1];
    g_bih[g] = (const float*)d_in[8 + g*4 + 2];
    g_bhh[g] = (const float*)d_in[8 + g*4 + 3];
  }
  const float* gat_wq[2] = {(const float*)d_in[24], (const float*)d_in[28]};
  const float* gat_bq[2] = {(const float*)d_in[25], (const float*)d_in[29]};
  const float* gat_wk[2] = {(const float*)d_in[26], (const float*)d_in[30]};
  const float* gat_bk[2] = {(const float*)d_in[27], (const float*)d_in[31]};
  const float* aff1 = (const float*)d_in[32];
  const float* aff2 = (const float*)d_in[33];
  const float* mw1  = (const float*)d_in[34];
  const float* mb1  = (const float*)d_in[35];
  const float* mw2  = (const float*)d_in[36];
  const float* mb2  = (const float*)d_in[37];
  const float* ow   = (const float*)d_in[38];
  const float* ob   = (const float*)d_in[39];
  float* out = (float*)d_out;

  // ---- workspace layout ----
  float* ws = (float*)d_ws;
  size_t off = 0;
  auto take = [&](size_t nf){ float* p = ws + off; off += nf; return p; };
  float* region = take(22552576);           // overlay region
  float* X0f  = region;                     // 2,097,152 (time-major layer-0 fwd)
  float* X0r  = region + 2097152;           // 2,097,152 (time-major layer-0 bwd)
  float* Qtb  = region + 4194304;           // 4 x 2,097,152
  float* Qtmp = region + 12582912;          // 2,097,152
  float* Htmp = region + 14680064;          // b-major H0 temp (early only)
  // finals overlay (sequential-phase buffers dead by then)
  float* T  = region;                       // 4,194,304
  float* Sb = region + 4194304;             // 1,048,576
  float* HH = region + 5242880;             // 4,194,304
  float* h1 = region + 9437184;             // 2,097,152
  float* h2 = region + 11534336;            // 2,097,152
  float* Ocat[2][2];                        // time-major H1 storage, stride 512
  for (int c = 0; c < 2; ++c) for (int l = 0; l < 2; ++l) Ocat[c][l] = take(4194304);
  float* S0b   = take(32768);               // 4 x 8192
  unsigned short* WtB  = (unsigned short*)take(786432);  // fp16 [cd][32][1536][8]
  unsigned short* WgkB = (unsigned short*)take(786432);  // fp16 [cd][32][1536][8]
  unsigned short* HhB  = (unsigned short*)take(4194304); // fp16 shadow [256][128][256]
  float* meanx = take(512);
  float* meany = take(512);
  float* invx  = take(8192);
  float* invy  = take(8192);
  float* dl    = take(8);
  float* Gbuf  = take(262144);

  // H0 = relu(F @ fc1w^T + fc1b)  (b-major temp), then spread to time-major
  gemm_k<false,true,true,false><<<dim3(4,64,1),256,0,stream>>>(
      F, fc1w, fc1b, Htmp, SD, SE, SE, SE, SD, 0,0,0);
  spread_k<<<SBN,256,0,stream>>>(Htmp, X0f, X0r);

  for (int l = 0; l < 2; ++l) {
    PTArgs pt, pg; StepArgs sta;
    sta.ldX = l ? SD2 : SD;
    sta.Wt = WtB; sta.Wgk = WgkB; sta.Hh = HhB;
    const int ldX = sta.ldX;
    for (int cd = 0; cd < 4; ++cd) {
      const int ch = cd >> 1;  // 0 = s-channel, 1 = l-channel
      const float* X = (l == 0) ? ((cd & 1) ? X0r : X0f)
                                : (Ocat[ch][0] + (cd & 1) * SD);
      const float* wq   = gat_wq[ch] + l * SD * SD;
      const float* bq   = gat_bq[ch] + l * SD;
      const float* wk   = gat_wk[ch] + l * SD * SD;
      const float* bk   = gat_bk[ch] + l * SD;
      const float* cwih = g_wih[ch*2+0] + l * SD3 * SD;
      const float* cwhh = g_whh[ch*2+0] + l * SD3 * SD;
      const float* cbih = g_bih[ch*2+0] + l * SD3;
      const float* cbhh = g_bhh[ch*2+0] + l * SD3;
      const float* pwih = g_wih[ch*2+1] + l * SD3 * SD;
      const float* pwhh = g_whh[ch*2+1] + l * SD3 * SD;
      const float* pbih = g_bih[ch*2+1] + l * SD3;
      const float* pbhh = g_bhh[ch*2+1] + l * SD3;
      pt.wc[cd] = cwhh; pt.wp[cd] = pwih;   // step-gate weights
      pg.wc[cd] = cwih; pg.wp[cd] = pwhh;   // GK weights
      // Qtmp = X@wq^T + bq ; Qt = Qtmp@wk ; S0 = Qtmp . bk
      gemm_k<false,true,false,false><<<dim3(4,64,1),256,0,stream>>>(
          X, wq, bq, Qtmp, SD, SD, ldX, SD, SD, 0,0,0);
      gemm_k<true,false,false,false><<<dim3(4,64,1),256,0,stream>>>(
          Qtmp, wk, nullptr, Qtb + (size_t)cd*2097152, SD, SD, SD, SD, SD, 0,0,0);
      s0_k<<<SBN/4,256,0,stream>>>(Qtmp, bk, S0b + cd*SBN);
      float* H1mut = Ocat[ch][l] + (cd & 1) * SD;
      sta.Qt[cd] = Qtb + (size_t)cd*2097152;
      sta.S0[cd] = S0b + cd*SBN;
      sta.H1[cd] = H1mut;
      sta.adj[cd] = ch ? adj2 : adj1; sta.rev[cd] = cd & 1;
      sta.bc[cd]  = cbhh; sta.bp[cd]  = pbih;
      sta.bgc[cd] = cbih; sta.bgp[cd] = pbhh;
      sta.X[cd] = X;
    }
    pt.Wt = WtB;  packT_k<<<dim3(32,4),256,0,stream>>>(pt);
    pg.Wt = WgkB; packT_k<<<dim3(32,4),256,0,stream>>>(pg);

    for (int s0 = 0; s0 < SN; s0 += CS) {
      sta.s0 = s0;
      step_chunk_k<<<256,256,SMEM_BYTES,stream>>>(sta);
    }
  }

  // diff loss (row-permutation invariant -> time-major OK)
  zero_k<<<1,256,0,stream>>>(dl, 2);
  for (int l = 0; l < 2; ++l) {
    zero_k<<<4,256,0,stream>>>(meanx, 1024);  // meanx+meany contiguous
    colmean_k<<<dim3(8,32,1),256,0,stream>>>(Ocat[0][l], meanx);
    colmean_k<<<dim3(8,32,1),256,0,stream>>>(Ocat[1][l], meany);
    rownorm_k<<<SBN/4,256,0,stream>>>(Ocat[0][l], meanx, invx);
    rownorm_k<<<SBN/4,256,0,stream>>>(Ocat[1][l], meany, invy);
    zero_k<<<256,256,0,stream>>>(Gbuf, (long)SD2*SD2);
    gpart_k<<<dim3(8,8,16),256,0,stream>>>(Ocat[0][l], Ocat[1][l], meanx, meany, invx, invy, Gbuf);
    sqsum_k<<<256,256,0,stream>>>(Gbuf, dl + l);
  }

  // cross attention + final MLP (h1 accumulated from F / HSn / HLn slices)
  gemm_k<true,false,false,false><<<dim3(8,64,1),256,0,stream>>>(
      Ocat[0][1], aff1, nullptr, T, SD2, SD2, SD2, SD2, SD2, 0,0,0);
  gemm_k<false,false,false,false><<<dim3(2,1,64),256,0,stream>>>(
      T, Ocat[1][1], nullptr, Sb, SN, SD2, 64*SD2, 64*SD2, SN, SD2, SD2, (long)SN*SN);
  smax_k<<<SBN/4,256,0,stream>>>(Sb);
  gemm_k<true,false,false,false><<<dim3(8,1,64),256,0,stream>>>(
      Sb, Ocat[1][1], nullptr, HH, SD2, SN, SN, 64*SD2, SD2, (long)SN*SN, SD2, (long)SN*SD2);
  gemm_k<false,true,false,false><<<dim3(4,64,1),256,0,stream>>>(
      F, mw1, mb1, h1, SD, SE, SE, SIN, SD, 0,0,0);
  gemm_k<false,false,false,true><<<dim3(4,64,1),256,0,stream>>>(
      HH, mw1 + 1024, nullptr, h1, SD, SD2, SD2, SIN, SD, 0,0,0);
  gemm_k<true,false,false,false><<<dim3(8,64,1),256,0,stream>>>(
      Ocat[1][1], aff2, nullptr, T, SD2, SD2, SD2, SD2, SD2, 0,0,0);
  gemm_k<false,false,false,false><<<dim3(2,1,64),256,0,stream>>>(
      T, Ocat[0][1], nullptr, Sb, SN, SD2, 64*SD2, 64*SD2, SN, SD2, SD2, (long)SN*SN);
  smax_k<<<SBN/4,256,0,stream>>>(Sb);
  gemm_k<true,false,false,false><<<dim3(8,1,64),256,0,stream>>>(
      Sb, Ocat[0][1], nullptr, HH, SD2, SN, SN, 64*SD2, SD2, (long)SN*SN, SD2, (long)SN*SD2);
  gemm_k<false,false,true,true><<<dim3(4,64,1),256,0,stream>>>(
      HH, mw1 + 1536, nullptr, h1, SD, SD2, SD2, SIN, SD, 0,0,0);
  gemm_k<false,true,true,false><<<dim3(4,64,1),256,0,stream>>>(
      h1, mw2, mb2, h2, SD, SD, SD, SD, SD, 0,0,0);
  head_k<<<SBN/4,256,0,stream>>>(h2, ow, ob, out);
  fin_k<<<1,1,0,stream>>>(dl, out + SBN * SNC);
}

// Round 7
// 5316.594 us; speedup vs baseline: 4.8526x; 4.8526x over previous
//
#include <hip/hip_runtime.h>
#include <hip/hip_fp16.h>
#include <math.h>

// Problem constants
#define SB   64     // batch
#define SN   128    // seq len
#define SE   1024   // feature dim
#define SD   256    // hidden D
#define SD2  512    // 2D
#define SD3  768    // 3D
#define SIN  2048   // 4D+E
#define SNC  7
#define SBN  8192   // SB*SN
#define CS   16     // chunk steps (GK tile held in LDS, fp16)

// dynamic LDS layout (bytes) for step_chunk_k
#define L_HS   0        // ushort[128*256] swizzled H shadow   (65536)
#define L_GK   65536    // ushort[CS*1536] GK tile             (49152)
#define L_XH   114688   // ushort[CS*256]  X tile              (8192)
#define L_QH   122880   // ushort[CS*256]  Q tile              (8192)
#define L_ADJ  131072   // float[CS*128]   adjacency masks     (8192)
#define L_MH   139264   // ushort[256]     M fp16              (512)
#define L_LGP  139776   // float[256]      score partials      (1024)
#define L_WGT  140800   // float[128]                          (512)
#define L_S0   141312   // float[16]                           (64)
#define SMEM_BYTES 141376

typedef _Float16 h2v __attribute__((ext_vector_type(2)));

__device__ __forceinline__ float wsum(float v){
#pragma unroll
  for (int o = 32; o; o >>= 1) v += __shfl_xor(v, o);
  return v;
}
__device__ __forceinline__ float sigm(float x){ return 1.f/(1.f + expf(-x)); }

__device__ __forceinline__ unsigned short f2h(float f){
  return __half_as_ushort(__float2half_rn(f));
}
__device__ __forceinline__ float h2f_(unsigned short u){
  return __half2float(__ushort_as_half(u));
}
__device__ __forceinline__ h2v u2h(unsigned u){
  union { unsigned u; h2v h; } c; c.u = u; return c.h;
}
// dot of 8 fp16 (uint4) with 8 packed fp16 (uint4), f32 accum
__device__ __forceinline__ float dot8d(uint4 w, uint4 m, float acc){
  acc = __builtin_amdgcn_fdot2(u2h(w.x), u2h(m.x), acc, false);
  acc = __builtin_amdgcn_fdot2(u2h(w.y), u2h(m.y), acc, false);
  acc = __builtin_amdgcn_fdot2(u2h(w.z), u2h(m.z), acc, false);
  acc = __builtin_amdgcn_fdot2(u2h(w.w), u2h(m.w), acc, false);
  return acc;
}

// ---------------------------------------------------------------------------
// Generic fp32 GEMM: C[M,N] = A @ op(B) (+bias)(+acc)(+relu), batched via z.
// ---------------------------------------------------------------------------
template<bool BKMAJ, bool BIAS, bool RELU, bool ACC>
__global__ __launch_bounds__(256)
void gemm_k(const float* __restrict__ A, const float* __restrict__ Bm,
            const float* __restrict__ bias, float* __restrict__ C,
            int Nn, int K, int lda, int ldb, int ldc,
            long sA, long sB, long sC)
{
  __shared__ float As[16][132];
  __shared__ float Bs[16][68];
  const int t  = threadIdx.x;
  const int tx = t & 15, ty = t >> 4;
  const float* Ab = A + (long)blockIdx.z * sA;
  const float* Bb = Bm + (long)blockIdx.z * sB;
  float* Cb = C + (long)blockIdx.z * sC;
  const int m0 = blockIdx.y * 128, n0 = blockIdx.x * 64;
  float acc[8][4];
#pragma unroll
  for (int i = 0; i < 8; ++i)
#pragma unroll
    for (int j = 0; j < 4; ++j) acc[i][j] = 0.f;

  const int am = t >> 1, ak = (t & 1) * 8;
  int bn_ = 0, bk_ = 0;
  if (BKMAJ) { bk_ = t >> 4; bn_ = (t & 15) * 4; }
  else       { bn_ = t >> 2; bk_ = (t & 3) * 4; }

  for (int k0 = 0; k0 < K; k0 += 16) {
    const float4 a0 = *(const float4*)(Ab + (long)(m0 + am) * lda + k0 + ak);
    const float4 a1 = *(const float4*)(Ab + (long)(m0 + am) * lda + k0 + ak + 4);
    float4 b0;
    if (BKMAJ) b0 = *(const float4*)(Bb + (long)(k0 + bk_) * ldb + n0 + bn_);
    else       b0 = *(const float4*)(Bb + (long)(n0 + bn_) * ldb + k0 + bk_);
    __syncthreads();
    As[ak+0][am] = a0.x; As[ak+1][am] = a0.y; As[ak+2][am] = a0.z; As[ak+3][am] = a0.w;
    As[ak+4][am] = a1.x; As[ak+5][am] = a1.y; As[ak+6][am] = a1.z; As[ak+7][am] = a1.w;
    if (BKMAJ) { *(float4*)&Bs[bk_][bn_] = b0; }
    else { Bs[bk_+0][bn_] = b0.x; Bs[bk_+1][bn_] = b0.y; Bs[bk_+2][bn_] = b0.z; Bs[bk_+3][bn_] = b0.w; }
    __syncthreads();
#pragma unroll
    for (int kk = 0; kk < 16; ++kk) {
      float av[8], bv[4];
      *(float4*)&av[0] = *(const float4*)&As[kk][ty*8];
      *(float4*)&av[4] = *(const float4*)&As[kk][ty*8+4];
      *(float4*)&bv[0] = *(const float4*)&Bs[kk][tx*4];
#pragma unroll
      for (int ii = 0; ii < 8; ++ii)
#pragma unroll
        for (int jj = 0; jj < 4; ++jj)
          acc[ii][jj] = fmaf(av[ii], bv[jj], acc[ii][jj]);
    }
  }
#pragma unroll
  for (int ii = 0; ii < 8; ++ii) {
#pragma unroll
    for (int jj = 0; jj < 4; ++jj) {
      float v = acc[ii][jj];
      if (BIAS) v += bias[n0 + tx*4 + jj];
      const long ci = (long)(m0 + ty*8 + ii) * ldc + n0 + tx*4 + jj;
      if (ACC) v += Cb[ci];
      if (RELU) v = fmaxf(v, 0.f);
      Cb[ci] = v;
    }
  }
}

// Htmp is b-major (row b*128+n). Write time-major X0f[(n*64+b)] and reversed.
__global__ void spread_k(const float* __restrict__ src, float* __restrict__ xf,
                         float* __restrict__ xr)
{
  const int r = blockIdx.x, t = threadIdx.x;   // src row = b*128+n
  const int b = r >> 7, n = r & 127;
  const float v = src[(long)r * SD + t];
  xf[((long)(n * 64 + b)) * SD + t] = v;
  xr[((long)((127 - n) * 64 + b)) * SD + t] = v;
}

// Pack transposed fp16 weights: Wt[cd][kb8][row][8] = fp16(W[row][kb8*8+q]),
// rows 0..767 from wc, 768..1535 from wp.  Grid (32 kb8, 4 cd).
struct PTArgs { const float* wc[4]; const float* wp[4]; unsigned short* Wt; };
__global__ void packT_k(PTArgs a)
{
  const int kb8 = blockIdx.x, cd = blockIdx.y, t = threadIdx.x;
#pragma unroll
  for (int p = 0; p < 6; ++p) {
    const int r = t + 256 * p;
    const float* src = (r < 768) ? (a.wc[cd] + (long)r * SD)
                                 : (a.wp[cd] + (long)(r - 768) * SD);
    const float4 v0 = *(const float4*)(src + kb8 * 8);
    const float4 v1 = *(const float4*)(src + kb8 * 8 + 4);
    uint4 o;
    o.x = (unsigned)f2h(v0.x) | ((unsigned)f2h(v0.y) << 16);
    o.y = (unsigned)f2h(v0.z) | ((unsigned)f2h(v0.w) << 16);
    o.z = (unsigned)f2h(v1.x) | ((unsigned)f2h(v1.y) << 16);
    o.w = (unsigned)f2h(v1.z) | ((unsigned)f2h(v1.w) << 16);
    *(uint4*)(a.Wt + (((size_t)cd * 32 + kb8) * 1536 + r) * 8) = o;
  }
}

// S0[m] = Q[m,:] . bk
__global__ void s0_k(const float* __restrict__ Q, const float* __restrict__ bk,
                     float* __restrict__ S0)
{
  const int r = blockIdx.x * 4 + (threadIdx.x >> 6), lane = threadIdx.x & 63;
  const float4 q  = *(const float4*)(Q + (long)r * SD + lane * 4);
  const float4 kb = *(const float4*)(bk + lane * 4);
  float p = q.x*kb.x + q.y*kb.y + q.z*kb.z + q.w*kb.w;
  p = wsum(p);
  if (lane == 0) S0[r] = p;
}

// ---------------------------------------------------------------------------
// Chunk step kernel (r5 verified base): CS sequential DAG steps per launch;
// chunked relaunch keeps 64 blocks/cd phase-locked -> weight stream L2-hit.
// THIS ROUND'S single change: D-phase prefetch depth 2 -> 4 (24 uint4 live
// only inside D; occupancy is LDS-capped at 1 block/CU so the extra VGPRs
// are free as long as we stay under the 256 spill cliff).
// ---------------------------------------------------------------------------
struct StepArgs {
  const float* Qt[4]; const float* S0[4];
  const int* adj[4]; int rev[4];
  const float* bc[4];  const float* bp[4];   // cbhh, pbih (step-gate biases)
  const float* bgc[4]; const float* bgp[4];  // cbih, pbhh (GK biases)
  const float* X[4];
  float* H1[4];                              // time-major stride SD2, col-offset baked
  unsigned short* Hh;                        // fp16 shadow [cd*64+b][128][256] (LINEAR)
  const unsigned short* Wt;   // fp16 [cd][32][1536][8]: rows 0..767 cwhh, 768..1535 pwih
  const unsigned short* Wgk;  // fp16 [cd][32][1536][8]: rows 0..767 cwih, 768..1535 pwhh
  int ldX, s0;
};
__global__ __launch_bounds__(256, 1) void step_chunk_k(StepArgs a)
{
  extern __shared__ __align__(16) char dsm[];
  unsigned short* Hs  = (unsigned short*)(dsm + L_HS);   // swizzled
  unsigned short* GKh = (unsigned short*)(dsm + L_GK);
  unsigned short* Xh  = (unsigned short*)(dsm + L_XH);
  unsigned short* Qh  = (unsigned short*)(dsm + L_QH);
  float* adjc = (float*)(dsm + L_ADJ);
  unsigned short* Mh  = (unsigned short*)(dsm + L_MH);
  float* lgp  = (float*)(dsm + L_LGP);
  float* wgt  = (float*)(dsm + L_WGT);
  float* s0s  = (float*)(dsm + L_S0);

  const int blk = blockIdx.x;
  const int cd = blk & 3, b = blk >> 2;
  const int t = threadIdx.x, j = t;       // output column 0..255
  const int ldX = a.ldX, c0 = a.s0;
  const float* Xp  = a.X[cd];
  float* H1 = a.H1[cd];
  unsigned short* Hg = a.Hh + ((size_t)(cd * 64 + b)) * 128 * 256;  // linear
  const float* Qtp = a.Qt[cd];
  const float* S0p = a.S0[cd];
  const int*   adjp = a.adj[cd];
  const int    rev  = a.rev[cd];

  // hoisted biases for this thread's column j
  const float bc0 = a.bc[cd][j],  bc1 = a.bc[cd][256+j],  bc2 = a.bc[cd][512+j];
  const float bp0 = a.bp[cd][j],  bp1 = a.bp[cd][256+j],  bp2 = a.bp[cd][512+j];

  // ---- prologue: stage X, Q (fp16), adjacency, S0; refill swizzled Hs ----
#pragma unroll
  for (int s = 0; s < CS; ++s) {
    Xh[s*256 + t] = f2h(Xp[((long)(c0+s)*64 + b)*ldX + t]);
    Qh[s*256 + t] = f2h(Qtp[((long)(c0+s)*64 + b)*SD + t]);
  }
  for (int z = t; z < CS*128; z += 256) {
    const int s = z >> 7, n = z & 127;
    const int i = c0 + s;
    int av = 0;
    if (i > 0) {
      const int ii = rev ? (SN-1-i) : i;
      const int nn = rev ? (SN-1-n) : n;
      av = adjp[((long)b*SN + ii)*SN + nn];
    }
    adjc[z] = (float)av;
  }
  if (t < CS) s0s[t] = S0p[(c0+t)*64 + b];
  for (int o = t*16; o < c0*512; o += 4096) {
    const uint4 v = *(const uint4*)((const char*)Hg + o);
    const int row = o >> 9, d2 = o & 511;
    *(uint4*)((char*)Hs + row*512 + (d2 ^ ((row & 31) << 4))) = v;
  }
  __syncthreads();

  // ---- GK phase: GKh[s][g*256+j] = X[c0+s,b] . Wgk_row(g*256+j) + bias ----
  {
    float gacc[6][CS];
#pragma unroll
    for (int g = 0; g < 6; ++g)
#pragma unroll
      for (int s = 0; s < CS; ++s) gacc[g][s] = 0.f;
    const unsigned short* wbase = a.Wgk + ((size_t)cd*32*1536 + j)*8;
    for (int kb8 = 0; kb8 < 32; ++kb8) {
      const uint4* wr = (const uint4*)(wbase + (size_t)kb8*12288);
      uint4 w[6];
#pragma unroll
      for (int g = 0; g < 6; ++g) w[g] = wr[g*256];   // gate stride 256 rows
#pragma unroll
      for (int s = 0; s < CS; ++s) {
        const uint4 x8 = *(const uint4*)&Xh[s*256 + kb8*8];
#pragma unroll
        for (int g = 0; g < 6; ++g)
          gacc[g][s] = dot8d(w[g], x8, gacc[g][s]);
      }
    }
#pragma unroll
    for (int g = 0; g < 6; ++g) {
      const float bg = (g < 3) ? a.bgc[cd][g*256 + j] : a.bgp[cd][(g-3)*256 + j];
#pragma unroll
      for (int s = 0; s < CS; ++s)
        GKh[s*1536 + g*256 + j] = f2h(gacc[g][s] + bg);
    }
  }
  __syncthreads();

  // ---- CS sequential steps ----
  for (int s = 0; s < CS; ++s) {
    const int i = c0 + s;
    float mreg = 0.f;
    if (i == 0) {
      Mh[t] = 0;
      __syncthreads();
    } else {
      // A: score — 2 threads/row, 16 kb8 each, swizzled LDS (2-way, free)
      {
        const int n = t & 127, hi = t >> 7;
        if (n < i) {
          const char* hrow = (const char*)Hs + n*512;
          const int cx = (n & 31) << 4;
          const unsigned short* qrow = Qh + s*256 + hi*128;
          float acc = 0.f;
#pragma unroll
          for (int k = 0; k < 16; ++k) {
            const uint4 hv = *(const uint4*)(hrow + (((hi*16 + k)*16) ^ cx));
            const uint4 qv = *(const uint4*)(qrow + k*8);
            acc = dot8d(hv, qv, acc);
          }
          lgp[t] = acc;
        }
      }
      __syncthreads();
      // B: softmax (wave 0)
      if (t < 64) {
        const float s0v = s0s[s];
        const int l = t;
        const float lg0 = lgp[l]      + lgp[128 + l];
        const float lg1 = lgp[64 + l] + lgp[192 + l];
        const float v0 = (l < i)    ? (lg0 + s0v - (1.f - adjc[s*128+l]   )*1e30f) : -3.0e38f;
        const float v1 = (l+64 < i) ? (lg1 + s0v - (1.f - adjc[s*128+l+64])*1e30f) : -3.0e38f;
        float mx = fmaxf(v0, v1);
#pragma unroll
        for (int o = 32; o; o >>= 1) mx = fmaxf(mx, __shfl_xor(mx, o));
        const float e0 = (l < i)    ? expf(v0 - mx) : 0.f;
        const float e1 = (l+64 < i) ? expf(v1 - mx) : 0.f;
        float sum = e0 + e1;
#pragma unroll
        for (int o = 32; o; o >>= 1) sum += __shfl_xor(sum, o);
        const float inv = 1.f / sum;
        if (l < i)    wgt[l]    = e0 * inv;
        if (l+64 < i) wgt[l+64] = e1 * inv;
      }
      __syncthreads();
      // C: M — per-thread column j from swizzled LDS, 4 accumulator chains
      {
        float m0 = 0.f, m1 = 0.f, m2 = 0.f, m3 = 0.f;
        int n = 0;
        for (; n + 4 <= i; n += 4) {
          m0 = fmaf(wgt[n+0], h2f_(Hs[(n+0)*256 + (j ^ (((n+0)&31)<<3))]), m0);
          m1 = fmaf(wgt[n+1], h2f_(Hs[(n+1)*256 + (j ^ (((n+1)&31)<<3))]), m1);
          m2 = fmaf(wgt[n+2], h2f_(Hs[(n+2)*256 + (j ^ (((n+2)&31)<<3))]), m2);
          m3 = fmaf(wgt[n+3], h2f_(Hs[(n+3)*256 + (j ^ (((n+3)&31)<<3))]), m3);
        }
        for (; n < i; ++n)
          m0 = fmaf(wgt[n], h2f_(Hs[n*256 + (j ^ ((n&31)<<3))]), m0);
        mreg = (m0 + m1) + (m2 + m3);
        Mh[t] = f2h(mreg);
      }
      __syncthreads();
    }

    // D: gates — 6 rows/thread, 4-deep round-robin register prefetch.
    // 24 uint4 live only inside this block (dead by E); occupancy is
    // LDS-capped so the VGPRs are free.  Prefetch distance ~3 iterations
    // (~350 cy) covers L2 latency; r5's distance-1 covered only ~120 cy.
    float g0 = 0.f, g1 = 0.f, g2 = 0.f, g3 = 0.f, g4 = 0.f, g5 = 0.f;
    {
      const unsigned short* wb = a.Wt + ((size_t)cd*32*1536 + j)*8;
      uint4 wA[6], wB[6], wC[6], wD[6];
      {
        const uint4* p0 = (const uint4*)wb;
        const uint4* p1 = (const uint4*)(wb + 12288);
        const uint4* p2 = (const uint4*)(wb + 24576);
        const uint4* p3 = (const uint4*)(wb + 36864);
#pragma unroll
        for (int g = 0; g < 6; ++g) {
          wA[g] = p0[g*256]; wB[g] = p1[g*256];
          wC[g] = p2[g*256]; wD[g] = p3[g*256];
        }
      }
      for (int kb = 0; kb < 32; kb += 4) {
        {
          const uint4 m8 = *(const uint4*)&Mh[kb*8];
          g0 = dot8d(wA[0], m8, g0); g1 = dot8d(wA[1], m8, g1);
          g2 = dot8d(wA[2], m8, g2); g3 = dot8d(wA[3], m8, g3);
          g4 = dot8d(wA[4], m8, g4); g5 = dot8d(wA[5], m8, g5);
          if (kb + 4 < 32) {
            const uint4* w = (const uint4*)(wb + (size_t)(kb+4)*12288);
#pragma unroll
            for (int g = 0; g < 6; ++g) wA[g] = w[g*256];
          }
        }
        {
          const uint4 m8 = *(const uint4*)&Mh[kb*8 + 8];
          g0 = dot8d(wB[0], m8, g0); g1 = dot8d(wB[1], m8, g1);
          g2 = dot8d(wB[2], m8, g2); g3 = dot8d(wB[3], m8, g3);
          g4 = dot8d(wB[4], m8, g4); g5 = dot8d(wB[5], m8, g5);
          if (kb + 5 < 32) {
            const uint4* w = (const uint4*)(wb + (size_t)(kb+5)*12288);
#pragma unroll
            for (int g = 0; g < 6; ++g) wB[g] = w[g*256];
          }
        }
        {
          const uint4 m8 = *(const uint4*)&Mh[kb*8 + 16];
          g0 = dot8d(wC[0], m8, g0); g1 = dot8d(wC[1], m8, g1);
          g2 = dot8d(wC[2], m8, g2); g3 = dot8d(wC[3], m8, g3);
          g4 = dot8d(wC[4], m8, g4); g5 = dot8d(wC[5], m8, g5);
          if (kb + 6 < 32) {
            const uint4* w = (const uint4*)(wb + (size_t)(kb+6)*12288);
#pragma unroll
            for (int g = 0; g < 6; ++g) wC[g] = w[g*256];
          }
        }
        {
          const uint4 m8 = *(const uint4*)&Mh[kb*8 + 24];
          g0 = dot8d(wD[0], m8, g0); g1 = dot8d(wD[1], m8, g1);
          g2 = dot8d(wD[2], m8, g2); g3 = dot8d(wD[3], m8, g3);
          g4 = dot8d(wD[4], m8, g4); g5 = dot8d(wD[5], m8, g5);
          if (kb + 7 < 32) {
            const uint4* w = (const uint4*)(wb + (size_t)(kb+7)*12288);
#pragma unroll
            for (int g = 0; g < 6; ++g) wD[g] = w[g*256];
          }
        }
      }
    }
    // E: GRU elementwise + H1 row write (fp32) + fp16 shadows (LDS + global)
    {
      const int sb = s*1536;
      const float gic_r = h2f_(GKh[sb + j]);
      const float gic_z = h2f_(GKh[sb + 256 + j]);
      const float gic_n = h2f_(GKh[sb + 512 + j]);
      const float ghp_r = h2f_(GKh[sb + 768 + j]);
      const float ghp_z = h2f_(GKh[sb + 1024 + j]);
      const float ghp_n = h2f_(GKh[sb + 1280 + j]);
      const float xj = Xp[((long)i*64 + b)*ldX + j];
      const float rC = sigm(gic_r + g0 + bc0);
      const float zC = sigm(gic_z + g1 + bc1);
      const float nC = tanhf(gic_n + rC * (g2 + bc2));
      const float Cc = (1.f - zC) * nC + zC * mreg;
      const float rP = sigm(g3 + bp0 + ghp_r);
      const float zP = sigm(g4 + bp1 + ghp_z);
      const float nP = tanhf(g5 + bp2 + rP * ghp_n);
      const float hval = Cc + (1.f - zP) * nP + zP * xj;
      H1[((long)i*64 + b)*SD2 + j] = hval;
      const unsigned short hh = f2h(hval);
      Hs[i*256 + (j ^ ((i & 31) << 3))] = hh;   // swizzled LDS
      Hg[(size_t)i*256 + j] = hh;               // linear global (next chunk)
    }
    __syncthreads();
  }
}

__global__ void zero_k(float* p, long n)
{
  for (long idx = (long)blockIdx.x * 256 + threadIdx.x; idx < n; idx += (long)gridDim.x * 256)
    p[idx] = 0.f;
}

// column means of (8192 x 512), grid (8 colblocks, 32 rowslices), atomicAdd
__global__ void colmean_k(const float* __restrict__ X, float* __restrict__ mean)
{
  __shared__ float red[256];
  const int c = blockIdx.x * 64 + (threadIdx.x & 63), rq = threadIdx.x >> 6;
  const int r0 = blockIdx.y * 256;
  float acc = 0.f;
  for (int r = r0 + rq; r < r0 + 256; r += 4) acc += X[(long)r * SD2 + c];
  red[threadIdx.x] = acc;
  __syncthreads();
  if (threadIdx.x < 64) {
    const float s = red[threadIdx.x] + red[64 + threadIdx.x] + red[128 + threadIdx.x] + red[192 + threadIdx.x];
    atomicAdd(&mean[c], s * (1.f / 8192.f));
  }
}

__global__ void rownorm_k(const float* __restrict__ X, const float* __restrict__ mean,
                          float* __restrict__ inv)
{
  const int r = blockIdx.x * 4 + (threadIdx.x >> 6), lane = threadIdx.x & 63;
  const float* xp = X + (long)r * SD2 + lane * 8;
  const float4 v0 = *(const float4*)xp;
  const float4 v1 = *(const float4*)(xp + 4);
  const float4 m0 = *(const float4*)(mean + lane * 8);
  const float4 m1 = *(const float4*)(mean + lane * 8 + 4);
  float ss = 0.f, d;
  d = v0.x - m0.x; ss += d*d;  d = v0.y - m0.y; ss += d*d;
  d = v0.z - m0.z; ss += d*d;  d = v0.w - m0.w; ss += d*d;
  d = v1.x - m1.x; ss += d*d;  d = v1.y - m1.y; ss += d*d;
  d = v1.z - m1.z; ss += d*d;  d = v1.w - m1.w; ss += d*d;
  ss = wsum(ss);
  if (lane == 0) inv[r] = 1.f / (sqrtf(ss) + 1e-6f);
}

// partial G += xhat^T yhat over K slice; grid (8, 8, 16)
__global__ __launch_bounds__(256)
void gpart_k(const float* __restrict__ X, const float* __restrict__ Y,
             const float* __restrict__ mx, const float* __restrict__ my,
             const float* __restrict__ ix, const float* __restrict__ iy,
             float* __restrict__ G)
{
  __shared__ float As[16][68];
  __shared__ float Bs[16][68];
  __shared__ float mxs[64], mys[64];
  const int t = threadIdx.x, tx = t & 15, ty = t >> 4;
  const int ci = blockIdx.y * 64, cj = blockIdx.x * 64;
  if (t < 64) { mxs[t] = mx[ci + t]; mys[t] = my[cj + t]; }
  float acc[4][4];
#pragma unroll
  for (int ii = 0; ii < 4; ++ii)
#pragma unroll
    for (int jj = 0; jj < 4; ++jj) acc[ii][jj] = 0.f;
  const int rl = t >> 4, c4 = (t & 15) * 4;
  __syncthreads();
  const int kend = blockIdx.z * 512 + 512;
  for (int kb = blockIdx.z * 512; kb < kend; kb += 16) {
    const int r = kb + rl;
    const float4 xv = *(const float4*)(X + (long)r * SD2 + ci + c4);
    const float4 yv = *(const float4*)(Y + (long)r * SD2 + cj + c4);
    const float vx = ix[r], vy = iy[r];
    __syncthreads();
    As[rl][c4+0] = (xv.x - mxs[c4+0]) * vx; As[rl][c4+1] = (xv.y - mxs[c4+1]) * vx;
    As[rl][c4+2] = (xv.z - mxs[c4+2]) * vx; As[rl][c4+3] = (xv.w - mxs[c4+3]) * vx;
    Bs[rl][c4+0] = (yv.x - mys[c4+0]) * vy; Bs[rl][c4+1] = (yv.y - mys[c4+1]) * vy;
    Bs[rl][c4+2] = (yv.z - mys[c4+2]) * vy; Bs[rl][c4+3] = (yv.w - mys[c4+3]) * vy;
    __syncthreads();
#pragma unroll
    for (int kk = 0; kk < 16; ++kk) {
      float av[4], bv[4];
      *(float4*)&av[0] = *(const float4*)&As[kk][ty*4];
      *(float4*)&bv[0] = *(const float4*)&Bs[kk][tx*4];
#pragma unroll
      for (int ii = 0; ii < 4; ++ii)
#pragma unroll
        for (int jj = 0; jj < 4; ++jj)
          acc[ii][jj] = fmaf(av[ii], bv[jj], acc[ii][jj]);
    }
  }
#pragma unroll
  for (int ii = 0; ii < 4; ++ii)
#pragma unroll
    for (int jj = 0; jj < 4; ++jj)
      atomicAdd(&G[(long)(ci + ty*4 + ii) * SD2 + cj + tx*4 + jj], acc[ii][jj]);
}

__global__ void sqsum_k(const float* __restrict__ G, float* __restrict__ dl)
{
  __shared__ float red[4];
  float s = 0.f;
  const long base = (long)blockIdx.x * 1024;
#pragma unroll
  for (int it = 0; it < 4; ++it) { const float v = G[base + it*256 + threadIdx.x]; s += v*v; }
  s = wsum(s);
  const int lane = threadIdx.x & 63, wv = threadIdx.x >> 6;
  if (lane == 0) red[wv] = s;
  __syncthreads();
  if (threadIdx.x == 0) atomicAdd(dl, red[0] + red[1] + red[2] + red[3]);
}

// softmax over rows of length 128 (in-place)
__global__ void smax_k(float* __restrict__ S)
{
  const int r = blockIdx.x * 4 + (threadIdx.x >> 6), lane = threadIdx.x & 63;
  float* p = S + (long)r * SN;
  const float v0 = p[lane], v1 = p[lane + 64];
  float mx = fmaxf(v0, v1);
#pragma unroll
  for (int o = 32; o; o >>= 1) mx = fmaxf(mx, __shfl_xor(mx, o));
  const float e0 = expf(v0 - mx), e1 = expf(v1 - mx);
  float s = e0 + e1;
#pragma unroll
  for (int o = 32; o; o >>= 1) s += __shfl_xor(s, o);
  const float inv = 1.f / s;
  p[lane] = e0 * inv; p[lane + 64] = e1 * inv;
}

__global__ void head_k(const float* __restrict__ H, const float* __restrict__ W,
                       const float* __restrict__ bo, float* __restrict__ out)
{
  const int r = blockIdx.x * 4 + (threadIdx.x >> 6), lane = threadIdx.x & 63;
  const float4 h = *(const float4*)(H + (long)r * SD + lane * 4);
#pragma unroll
  for (int c = 0; c < SNC; ++c) {
    const float4 w = *(const float4*)(W + (long)c * SD + lane * 4);
    float p = h.x*w.x + h.y*w.y + h.z*w.z + h.w*w.w;
    p = wsum(p);
    if (lane == 0) out[(long)r * SNC + c] = p + bo[c];
  }
}

__global__ void fin_k(const float* __restrict__ dl, float* __restrict__ out)
{
  out[0] = (dl[0] + dl[1]) * (0.3f / (512.f * 512.f));
}

// ---------------------------------------------------------------------------
extern "C" void kernel_launch(void* const* d_in, const int* in_sizes, int n_in,
                              void* d_out, int out_size, void* d_ws, size_t ws_size,
                              hipStream_t stream)
{
  (void)in_sizes; (void)n_in; (void)out_size; (void)ws_size;

  static bool attr_set = false;
  if (!attr_set) {
    hipFuncSetAttribute(reinterpret_cast<const void*>(step_chunk_k),
                        hipFuncAttributeMaxDynamicSharedMemorySize, SMEM_BYTES);
    attr_set = true;
  }

  const float* F    = (const float*)d_in[0];
  const int*   adj1 = (const int*)  d_in[1];
  const int*   adj2 = (const int*)  d_in[2];
  const float* fc1w = (const float*)d_in[6];
  const float* fc1b = (const float*)d_in[7];
  const float *g_wih[4], *g_whh[4], *g_bih[4], *g_bhh[4];  // gcs, gps, gcl, gpl
  for (int g = 0; g < 4; ++g) {
    g_wih[g] = (const float*)d_in[8 + g*4 + 0];
    g_whh[g] = (const float*)d_in[8 + g*4 + 1];
    g_bih[g] = (const float*)d_in[8 + g*4 + 2];
    g_bhh[g] = (const float*)d_in[8 + g*4 + 3];
  }
  const float* gat_wq[2] = {(const float*)d_in[24], (const float*)d_in[28]};
  const float* gat_bq[2] = {(const float*)d_in[25], (const float*)d_in[29]};
  const float* gat_wk[2] = {(const float*)d_in[26], (const float*)d_in[30]};
  const float* gat_bk[2] = {(const float*)d_in[27], (const float*)d_in[31]};
  const float* aff1 = (const float*)d_in[32];
  const float* aff2 = (const float*)d_in[33];
  const float* mw1  = (const float*)d_in[34];
  const float* mb1  = (const float*)d_in[35];
  const float* mw2  = (const float*)d_in[36];
  const float* mb2  = (const float*)d_in[37];
  const float* ow   = (const float*)d_in[38];
  const float* ob   = (const float*)d_in[39];
  float* out = (float*)d_out;

  // ---- workspace layout ----
  float* ws = (float*)d_ws;
  size_t off = 0;
  auto take = [&](size_t nf){ float* p = ws + off; off += nf; return p; };
  float* region = take(22552576);           // overlay region
  float* X0f  = region;                     // 2,097,152 (time-major layer-0 fwd)
  float* X0r  = region + 2097152;           // 2,097,152 (time-major layer-0 bwd)
  float* Qtb  = region + 4194304;           // 4 x 2,097,152
  float* Qtmp = region + 12582912;          // 2,097,152
  float* Htmp = region + 14680064;          // b-major H0 temp (early only)
  // finals overlay (sequential-phase buffers dead by then)
  float* T  = region;                       // 4,194,304
  float* Sb = region + 4194304;             // 1,048,576
  float* HH = region + 5242880;             // 4,194,304
  float* h1 = region + 9437184;             // 2,097,152
  float* h2 = region + 11534336;            // 2,097,152
  float* Ocat[2][2];                        // time-major H1 storage, stride 512
  for (int c = 0; c < 2; ++c) for (int l = 0; l < 2; ++l) Ocat[c][l] = take(4194304);
  float* S0b   = take(32768);               // 4 x 8192
  unsigned short* WtB  = (unsigned short*)take(786432);  // fp16 [cd][32][1536][8]
  unsigned short* WgkB = (unsigned short*)take(786432);  // fp16 [cd][32][1536][8]
  unsigned short* HhB  = (unsigned short*)take(4194304); // fp16 shadow [256][128][256]
  float* meanx = take(512);
  float* meany = take(512);
  float* invx  = take(8192);
  float* invy  = take(8192);
  float* dl    = take(8);
  float* Gbuf  = take(262144);

  // H0 = relu(F @ fc1w^T + fc1b)  (b-major temp), then spread to time-major
  gemm_k<false,true,true,false><<<dim3(4,64,1),256,0,stream>>>(
      F, fc1w, fc1b, Htmp, SD, SE, SE, SE, SD, 0,0,0);
  spread_k<<<SBN,256,0,stream>>>(Htmp, X0f, X0r);

  for (int l = 0; l < 2; ++l) {
    PTArgs pt, pg; StepArgs sta;
    sta.ldX = l ? SD2 : SD;
    sta.Wt = WtB; sta.Wgk = WgkB; sta.Hh = HhB;
    const int ldX = sta.ldX;
    for (int cd = 0; cd < 4; ++cd) {
      const int ch = cd >> 1;  // 0 = s-channel, 1 = l-channel
      const float* X = (l == 0) ? ((cd & 1) ? X0r : X0f)
                                : (Ocat[ch][0] + (cd & 1) * SD);
      const float* wq   = gat_wq[ch] + l * SD * SD;
      const float* bq   = gat_bq[ch] + l * SD;
      const float* wk   = gat_wk[ch] + l * SD * SD;
      const float* bk   = gat_bk[ch] + l * SD;
      const float* cwih = g_wih[ch*2+0] + l * SD3 * SD;
      const float* cwhh = g_whh[ch*2+0] + l * SD3 * SD;
      const float* cbih = g_bih[ch*2+0] + l * SD3;
      const float* cbhh = g_bhh[ch*2+0] + l * SD3;
      const float* pwih = g_wih[ch*2+1] + l * SD3 * SD;
      const float* pwhh = g_whh[ch*2+1] + l * SD3 * SD;
      const float* pbih = g_bih[ch*2+1] + l * SD3;
      const float* pbhh = g_bhh[ch*2+1] + l * SD3;
      pt.wc[cd] = cwhh; pt.wp[cd] = pwih;   // step-gate weights
      pg.wc[cd] = cwih; pg.wp[cd] = pwhh;   // GK weights
      // Qtmp = X@wq^T + bq ; Qt = Qtmp@wk ; S0 = Qtmp . bk
      gemm_k<false,true,false,false><<<dim3(4,64,1),256,0,stream>>>(
          X, wq, bq, Qtmp, SD, SD, ldX, SD, SD, 0,0,0);
      gemm_k<true,false,false,false><<<dim3(4,64,1),256,0,stream>>>(
          Qtmp, wk, nullptr, Qtb + (size_t)cd*2097152, SD, SD, SD, SD, SD, 0,0,0);
      s0_k<<<SBN/4,256,0,stream>>>(Qtmp, bk, S0b + cd*SBN);
      float* H1mut = Ocat[ch][l] + (cd & 1) * SD;
      sta.Qt[cd] = Qtb + (size_t)cd*2097152;
      sta.S0[cd] = S0b + cd*SBN;
      sta.H1[cd] = H1mut;
      sta.adj[cd] = ch ? adj2 : adj1; sta.rev[cd] = cd & 1;
      sta.bc[cd]  = cbhh; sta.bp[cd]  = pbih;
      sta.bgc[cd] = cbih; sta.bgp[cd] = pbhh;
      sta.X[cd] = X;
    }
    pt.Wt = WtB;  packT_k<<<dim3(32,4),256,0,stream>>>(pt);
    pg.Wt = WgkB; packT_k<<<dim3(32,4),256,0,stream>>>(pg);

    for (int s0 = 0; s0 < SN; s0 += CS) {
      sta.s0 = s0;
      step_chunk_k<<<256,256,SMEM_BYTES,stream>>>(sta);
    }
  }

  // diff loss (row-permutation invariant -> time-major OK)
  zero_k<<<1,256,0,stream>>>(dl, 2);
  for (int l = 0; l < 2; ++l) {
    zero_k<<<4,256,0,stream>>>(meanx, 1024);  // meanx+meany contiguous
    colmean_k<<<dim3(8,32,1),256,0,stream>>>(Ocat[0][l], meanx);
    colmean_k<<<dim3(8,32,1),256,0,stream>>>(Ocat[1][l], meany);
    rownorm_k<<<SBN/4,256,0,stream>>>(Ocat[0][l], meanx, invx);
    rownorm_k<<<SBN/4,256,0,stream>>>(Ocat[1][l], meany, invy);
    zero_k<<<256,256,0,stream>>>(Gbuf, (long)SD2*SD2);
    gpart_k<<<dim3(8,8,16),256,0,stream>>>(Ocat[0][l], Ocat[1][l], meanx, meany, invx, invy, Gbuf);
    sqsum_k<<<256,256,0,stream>>>(Gbuf, dl + l);
  }

  // cross attention + final MLP (h1 accumulated from F / HSn / HLn slices)
  gemm_k<true,false,false,false><<<dim3(8,64,1),256,0,stream>>>(
      Ocat[0][1], aff1, nullptr, T, SD2, SD2, SD2, SD2, SD2, 0,0,0);
  gemm_k<false,false,false,false><<<dim3(2,1,64),256,0,stream>>>(
      T, Ocat[1][1], nullptr, Sb, SN, SD2, 64*SD2, 64*SD2, SN, SD2, SD2, (long)SN*SN);
  smax_k<<<SBN/4,256,0,stream>>>(Sb);
  gemm_k<true,false,false,false><<<dim3(8,1,64),256,0,stream>>>(
      Sb, Ocat[1][1], nullptr, HH, SD2, SN, SN, 64*SD2, SD2, (long)SN*SN, SD2, (long)SN*SD2);
  gemm_k<false,true,false,false><<<dim3(4,64,1),256,0,stream>>>(
      F, mw1, mb1, h1, SD, SE, SE, SIN, SD, 0,0,0);
  gemm_k<false,false,false,true><<<dim3(4,64,1),256,0,stream>>>(
      HH, mw1 + 1024, nullptr, h1, SD, SD2, SD2, SIN, SD, 0,0,0);
  gemm_k<true,false,false,false><<<dim3(8,64,1),256,0,stream>>>(
      Ocat[1][1], aff2, nullptr, T, SD2, SD2, SD2, SD2, SD2, 0,0,0);
  gemm_k<false,false,false,false><<<dim3(2,1,64),256,0,stream>>>(
      T, Ocat[0][1], nullptr, Sb, SN, SD2, 64*SD2, 64*SD2, SN, SD2, SD2, (long)SN*SN);
  smax_k<<<SBN/4,256,0,stream>>>(Sb);
  gemm_k<true,false,false,false><<<dim3(8,1,64),256,0,stream>>>(
      Sb, Ocat[0][1], nullptr, HH, SD2, SN, SN, 64*SD2, SD2, (long)SN*SN, SD2, (long)SN*SD2);
  gemm_k<false,false,true,true><<<dim3(4,64,1),256,0,stream>>>(
      HH, mw1 + 1536, nullptr, h1, SD, SD2, SD2, SIN, SD, 0,0,0);
  gemm_k<false,true,true,false><<<dim3(4,64,1),256,0,stream>>>(
      h1, mw2, mb2, h2, SD, SD, SD, SD, SD, 0,0,0);
  head_k<<<SBN/4,256,0,stream>>>(h2, ow, ob, out);
  fin_k<<<1,1,0,stream>>>(dl, out + SBN * SNC);
}

// Round 8
// 4553.069 us; speedup vs baseline: 5.6664x; 1.1677x over previous
//
#include <hip/hip_runtime.h>
#include <hip/hip_fp16.h>
#include <math.h>

// Problem constants
#define SB   64     // batch
#define SN   128    // seq len
#define SE   1024   // feature dim
#define SD   256    // hidden D
#define SD2  512    // 2D
#define SD3  768    // 3D
#define SIN  2048   // 4D+E
#define SNC  7
#define SBN  8192   // SB*SN
#define CS   16     // chunk steps (GK tile held in LDS, fp16)

// dynamic LDS layout (bytes) for step_chunk_k (512 threads)
#define L_HS   0        // ushort[128*256] swizzled H shadow   (65536)
#define L_GK   65536    // ushort[CS*1536] GK tile             (49152)
#define L_XH   114688   // ushort[CS*256]  X tile              (8192)
#define L_QH   122880   // ushort[CS*256]  Q tile              (8192)
#define L_ADJ  131072   // float[CS*128]   adjacency masks     (8192)
#define L_MH   139264   // ushort[256]     M fp16              (512)
#define L_LGP  139776   // float[512]      score partials      (2048)
#define L_MP   141824   // float[512]      M partials          (2048)
#define L_WGT  143872   // float[128]                          (512)
#define L_PBUF 144384   // float[256]      P-GRU halves        (1024)
#define L_S0   145408   // float[16]                           (64)
#define SMEM_BYTES 145472

typedef _Float16 h2v __attribute__((ext_vector_type(2)));

__device__ __forceinline__ float wsum(float v){
#pragma unroll
  for (int o = 32; o; o >>= 1) v += __shfl_xor(v, o);
  return v;
}
__device__ __forceinline__ float sigm(float x){ return 1.f/(1.f + expf(-x)); }

__device__ __forceinline__ unsigned short f2h(float f){
  return __half_as_ushort(__float2half_rn(f));
}
__device__ __forceinline__ float h2f_(unsigned short u){
  return __half2float(__ushort_as_half(u));
}
__device__ __forceinline__ h2v u2h(unsigned u){
  union { unsigned u; h2v h; } c; c.u = u; return c.h;
}
// dot of 8 fp16 (uint4) with 8 packed fp16 (uint4), f32 accum
__device__ __forceinline__ float dot8d(uint4 w, uint4 m, float acc){
  acc = __builtin_amdgcn_fdot2(u2h(w.x), u2h(m.x), acc, false);
  acc = __builtin_amdgcn_fdot2(u2h(w.y), u2h(m.y), acc, false);
  acc = __builtin_amdgcn_fdot2(u2h(w.z), u2h(m.z), acc, false);
  acc = __builtin_amdgcn_fdot2(u2h(w.w), u2h(m.w), acc, false);
  return acc;
}

// ---------------------------------------------------------------------------
// Generic fp32 GEMM: C[M,N] = A @ op(B) (+bias)(+acc)(+relu), batched via z.
// ---------------------------------------------------------------------------
template<bool BKMAJ, bool BIAS, bool RELU, bool ACC>
__global__ __launch_bounds__(256)
void gemm_k(const float* __restrict__ A, const float* __restrict__ Bm,
            const float* __restrict__ bias, float* __restrict__ C,
            int Nn, int K, int lda, int ldb, int ldc,
            long sA, long sB, long sC)
{
  __shared__ float As[16][132];
  __shared__ float Bs[16][68];
  const int t  = threadIdx.x;
  const int tx = t & 15, ty = t >> 4;
  const float* Ab = A + (long)blockIdx.z * sA;
  const float* Bb = Bm + (long)blockIdx.z * sB;
  float* Cb = C + (long)blockIdx.z * sC;
  const int m0 = blockIdx.y * 128, n0 = blockIdx.x * 64;
  float acc[8][4];
#pragma unroll
  for (int i = 0; i < 8; ++i)
#pragma unroll
    for (int j = 0; j < 4; ++j) acc[i][j] = 0.f;

  const int am = t >> 1, ak = (t & 1) * 8;
  int bn_ = 0, bk_ = 0;
  if (BKMAJ) { bk_ = t >> 4; bn_ = (t & 15) * 4; }
  else       { bn_ = t >> 2; bk_ = (t & 3) * 4; }

  for (int k0 = 0; k0 < K; k0 += 16) {
    const float4 a0 = *(const float4*)(Ab + (long)(m0 + am) * lda + k0 + ak);
    const float4 a1 = *(const float4*)(Ab + (long)(m0 + am) * lda + k0 + ak + 4);
    float4 b0;
    if (BKMAJ) b0 = *(const float4*)(Bb + (long)(k0 + bk_) * ldb + n0 + bn_);
    else       b0 = *(const float4*)(Bb + (long)(n0 + bn_) * ldb + k0 + bk_);
    __syncthreads();
    As[ak+0][am] = a0.x; As[ak+1][am] = a0.y; As[ak+2][am] = a0.z; As[ak+3][am] = a0.w;
    As[ak+4][am] = a1.x; As[ak+5][am] = a1.y; As[ak+6][am] = a1.z; As[ak+7][am] = a1.w;
    if (BKMAJ) { *(float4*)&Bs[bk_][bn_] = b0; }
    else { Bs[bk_+0][bn_] = b0.x; Bs[bk_+1][bn_] = b0.y; Bs[bk_+2][bn_] = b0.z; Bs[bk_+3][bn_] = b0.w; }
    __syncthreads();
#pragma unroll
    for (int kk = 0; kk < 16; ++kk) {
      float av[8], bv[4];
      *(float4*)&av[0] = *(const float4*)&As[kk][ty*8];
      *(float4*)&av[4] = *(const float4*)&As[kk][ty*8+4];
      *(float4*)&bv[0] = *(const float4*)&Bs[kk][tx*4];
#pragma unroll
      for (int ii = 0; ii < 8; ++ii)
#pragma unroll
        for (int jj = 0; jj < 4; ++jj)
          acc[ii][jj] = fmaf(av[ii], bv[jj], acc[ii][jj]);
    }
  }
#pragma unroll
  for (int ii = 0; ii < 8; ++ii) {
#pragma unroll
    for (int jj = 0; jj < 4; ++jj) {
      float v = acc[ii][jj];
      if (BIAS) v += bias[n0 + tx*4 + jj];
      const long ci = (long)(m0 + ty*8 + ii) * ldc + n0 + tx*4 + jj;
      if (ACC) v += Cb[ci];
      if (RELU) v = fmaxf(v, 0.f);
      Cb[ci] = v;
    }
  }
}

// Htmp is b-major (row b*128+n). Write time-major X0f[(n*64+b)] and reversed.
__global__ void spread_k(const float* __restrict__ src, float* __restrict__ xf,
                         float* __restrict__ xr)
{
  const int r = blockIdx.x, t = threadIdx.x;   // src row = b*128+n
  const int b = r >> 7, n = r & 127;
  const float v = src[(long)r * SD + t];
  xf[((long)(n * 64 + b)) * SD + t] = v;
  xr[((long)((127 - n) * 64 + b)) * SD + t] = v;
}

// Pack transposed fp16 weights: Wt[cd][kb8][row][8] = fp16(W[row][kb8*8+q]),
// rows 0..767 from wc, 768..1535 from wp.  Grid (32 kb8, 4 cd).
struct PTArgs { const float* wc[4]; const float* wp[4]; unsigned short* Wt; };
__global__ void packT_k(PTArgs a)
{
  const int kb8 = blockIdx.x, cd = blockIdx.y, t = threadIdx.x;
#pragma unroll
  for (int p = 0; p < 6; ++p) {
    const int r = t + 256 * p;
    const float* src = (r < 768) ? (a.wc[cd] + (long)r * SD)
                                 : (a.wp[cd] + (long)(r - 768) * SD);
    const float4 v0 = *(const float4*)(src + kb8 * 8);
    const float4 v1 = *(const float4*)(src + kb8 * 8 + 4);
    uint4 o;
    o.x = (unsigned)f2h(v0.x) | ((unsigned)f2h(v0.y) << 16);
    o.y = (unsigned)f2h(v0.z) | ((unsigned)f2h(v0.w) << 16);
    o.z = (unsigned)f2h(v1.x) | ((unsigned)f2h(v1.y) << 16);
    o.w = (unsigned)f2h(v1.z) | ((unsigned)f2h(v1.w) << 16);
    *(uint4*)(a.Wt + (((size_t)cd * 32 + kb8) * 1536 + r) * 8) = o;
  }
}

// S0[m] = Q[m,:] . bk
__global__ void s0_k(const float* __restrict__ Q, const float* __restrict__ bk,
                     float* __restrict__ S0)
{
  const int r = blockIdx.x * 4 + (threadIdx.x >> 6), lane = threadIdx.x & 63;
  const float4 q  = *(const float4*)(Q + (long)r * SD + lane * 4);
  const float4 kb = *(const float4*)(bk + lane * 4);
  float p = q.x*kb.x + q.y*kb.y + q.z*kb.z + q.w*kb.w;
  p = wsum(p);
  if (lane == 0) S0[r] = p;
}

// ---------------------------------------------------------------------------
// Chunk step kernel, 512 threads (8 waves = 2/SIMD): halves-split (r4's
// parallelism) x chunked relaunch (r5's L2 locality) — the untried quadrant.
// half 0 (t<256): C-GRU gate rows (cwhh) + M-combine + final h write.
// half 1 (t>=256): P-GRU gate rows (pwih) -> pbuf.
// GK split by gate halves (disjoint outputs).  Score 4 threads/row.
// M phase parity-split with LDS partial reduce.  D keeps r5's verified
// 2-stage prefetch (now 3 rows/thread).  Chunked relaunch keeps all blocks
// within a 16-step window -> weight set stays L2-resident (r4's persistent
// variant de-phased and thrashed L2; this avoids that).
// ---------------------------------------------------------------------------
struct StepArgs {
  const float* Qt[4]; const float* S0[4];
  const int* adj[4]; int rev[4];
  const float* bc[4];  const float* bp[4];   // cbhh, pbih (step-gate biases)
  const float* bgc[4]; const float* bgp[4];  // cbih, pbhh (GK biases)
  const float* X[4];
  float* H1[4];                              // time-major stride SD2, col-offset baked
  unsigned short* Hh;                        // fp16 shadow [cd*64+b][128][256] (LINEAR)
  const unsigned short* Wt;   // fp16 [cd][32][1536][8]: rows 0..767 cwhh, 768..1535 pwih
  const unsigned short* Wgk;  // fp16 [cd][32][1536][8]: rows 0..767 cwih, 768..1535 pwhh
  int ldX, s0;
};
__global__ __launch_bounds__(512, 1) void step_chunk_k(StepArgs a)
{
  extern __shared__ __align__(16) char dsm[];
  unsigned short* Hs  = (unsigned short*)(dsm + L_HS);   // swizzled
  unsigned short* GKh = (unsigned short*)(dsm + L_GK);
  unsigned short* Xh  = (unsigned short*)(dsm + L_XH);
  unsigned short* Qh  = (unsigned short*)(dsm + L_QH);
  float* adjc = (float*)(dsm + L_ADJ);
  unsigned short* Mh  = (unsigned short*)(dsm + L_MH);
  float* lgp  = (float*)(dsm + L_LGP);
  float* Mp   = (float*)(dsm + L_MP);
  float* wgt  = (float*)(dsm + L_WGT);
  float* pbuf = (float*)(dsm + L_PBUF);
  float* s0s  = (float*)(dsm + L_S0);

  const int blk = blockIdx.x;
  const int cd = blk & 3, b = blk >> 2;
  const int t = threadIdx.x;
  const int half = t >> 8, j = t & 255;   // output column 0..255
  const int ldX = a.ldX, c0 = a.s0;
  const float* Xp  = a.X[cd];
  float* H1 = a.H1[cd];
  unsigned short* Hg = a.Hh + ((size_t)(cd * 64 + b)) * 128 * 256;  // linear
  const float* Qtp = a.Qt[cd];
  const float* S0p = a.S0[cd];
  const int*   adjp = a.adj[cd];
  const int    rev  = a.rev[cd];

  // per-half biases: half0 = C-GRU (cbhh step-gates, cbih GK),
  //                  half1 = P-GRU (pbih step-gates, pbhh GK)
  float eb0, eb1, eb2, gb0, gb1, gb2;
  if (half == 0) {
    eb0 = a.bc[cd][j];  eb1 = a.bc[cd][256+j];  eb2 = a.bc[cd][512+j];
    gb0 = a.bgc[cd][j]; gb1 = a.bgc[cd][256+j]; gb2 = a.bgc[cd][512+j];
  } else {
    eb0 = a.bp[cd][j];  eb1 = a.bp[cd][256+j];  eb2 = a.bp[cd][512+j];
    gb0 = a.bgp[cd][j]; gb1 = a.bgp[cd][256+j]; gb2 = a.bgp[cd][512+j];
  }
  const unsigned short* wb   = a.Wt  + ((size_t)cd*32*1536 + half*768 + j)*8;
  const unsigned short* wbgk = a.Wgk + ((size_t)cd*32*1536 + half*768 + j)*8;

  // ---- prologue: stage X, Q (fp16), adjacency, S0; refill swizzled Hs ----
  for (int z = t; z < CS*256; z += 512) {
    const int s = z >> 8, c = z & 255;
    Xh[z] = f2h(Xp[((long)(c0+s)*64 + b)*ldX + c]);
    Qh[z] = f2h(Qtp[((long)(c0+s)*64 + b)*SD + c]);
  }
  for (int z = t; z < CS*128; z += 512) {
    const int s = z >> 7, n = z & 127;
    const int i = c0 + s;
    int av = 0;
    if (i > 0) {
      const int ii = rev ? (SN-1-i) : i;
      const int nn = rev ? (SN-1-n) : n;
      av = adjp[((long)b*SN + ii)*SN + nn];
    }
    adjc[z] = (float)av;
  }
  if (t < CS) s0s[t] = S0p[(c0+t)*64 + b];
  for (int o = t*16; o < c0*512; o += 8192) {
    const uint4 v = *(const uint4*)((const char*)Hg + o);
    const int row = o >> 9, d2 = o & 511;
    *(uint4*)((char*)Hs + row*512 + (d2 ^ ((row & 31) << 4))) = v;
  }
  __syncthreads();

  // ---- GK phase: 3 gate rows per thread (half-split, disjoint outputs) ----
  {
    float gacc[3][CS];
#pragma unroll
    for (int g = 0; g < 3; ++g)
#pragma unroll
      for (int s = 0; s < CS; ++s) gacc[g][s] = 0.f;
    for (int kb8 = 0; kb8 < 32; ++kb8) {
      const uint4* wr = (const uint4*)(wbgk + (size_t)kb8*12288);
      const uint4 w0 = wr[0], w1 = wr[256], w2 = wr[512];
#pragma unroll
      for (int s = 0; s < CS; ++s) {
        const uint4 x8 = *(const uint4*)&Xh[s*256 + kb8*8];
        gacc[0][s] = dot8d(w0, x8, gacc[0][s]);
        gacc[1][s] = dot8d(w1, x8, gacc[1][s]);
        gacc[2][s] = dot8d(w2, x8, gacc[2][s]);
      }
    }
    const float gb[3] = {gb0, gb1, gb2};
#pragma unroll
    for (int g = 0; g < 3; ++g)
#pragma unroll
      for (int s = 0; s < CS; ++s)
        GKh[s*1536 + (half*3 + g)*256 + j] = f2h(gacc[g][s] + gb[g]);
  }
  __syncthreads();

  // ---- CS sequential steps ----
  for (int s = 0; s < CS; ++s) {
    const int i = c0 + s;
    const float xj = Xp[((long)i*64 + b)*ldX + j];
    float mreg = 0.f;
    if (i == 0) {
      if (t < 256) Mh[t] = 0;
      __syncthreads();
    } else {
      // A: score — 4 threads/row, 8 kb8 each, swizzled LDS (2-way, free)
      {
        const int n = t & 127, q4 = t >> 7;   // q4 in 0..3
        if (n < i) {
          const char* hrow = (const char*)Hs + n*512;
          const int cx = (n & 31) << 4;
          const unsigned short* qrow = Qh + s*256 + q4*64;
          float acc = 0.f;
#pragma unroll
          for (int k = 0; k < 8; ++k) {
            const uint4 hv = *(const uint4*)(hrow + (((q4*8 + k)*16) ^ cx));
            const uint4 qv = *(const uint4*)(qrow + k*8);
            acc = dot8d(hv, qv, acc);
          }
          lgp[t] = acc;
        }
      }
      __syncthreads();
      // B: softmax (wave 0)
      if (t < 64) {
        const float s0v = s0s[s];
        const int l = t;
        const float lg0 = (lgp[l]      + lgp[128 + l]) + (lgp[256 + l] + lgp[384 + l]);
        const float lg1 = (lgp[64 + l] + lgp[192 + l]) + (lgp[320 + l] + lgp[448 + l]);
        const float v0 = (l < i)    ? (lg0 + s0v - (1.f - adjc[s*128+l]   )*1e30f) : -3.0e38f;
        const float v1 = (l+64 < i) ? (lg1 + s0v - (1.f - adjc[s*128+l+64])*1e30f) : -3.0e38f;
        float mx = fmaxf(v0, v1);
#pragma unroll
        for (int o = 32; o; o >>= 1) mx = fmaxf(mx, __shfl_xor(mx, o));
        const float e0 = (l < i)    ? expf(v0 - mx) : 0.f;
        const float e1 = (l+64 < i) ? expf(v1 - mx) : 0.f;
        float sum = e0 + e1;
#pragma unroll
        for (int o = 32; o; o >>= 1) sum += __shfl_xor(sum, o);
        const float inv = 1.f / sum;
        if (l < i)    wgt[l]    = e0 * inv;
        if (l+64 < i) wgt[l+64] = e1 * inv;
      }
      __syncthreads();
      // C: M — parity-split over n (half=even/odd), 4 accumulator chains
      {
        float m0 = 0.f, m1 = 0.f, m2 = 0.f, m3 = 0.f;
        int n = half;
        for (; n + 6 < i; n += 8) {
          m0 = fmaf(wgt[n],   h2f_(Hs[(n  )*256 + (j ^ (((n  )&31)<<3))]), m0);
          m1 = fmaf(wgt[n+2], h2f_(Hs[(n+2)*256 + (j ^ (((n+2)&31)<<3))]), m1);
          m2 = fmaf(wgt[n+4], h2f_(Hs[(n+4)*256 + (j ^ (((n+4)&31)<<3))]), m2);
          m3 = fmaf(wgt[n+6], h2f_(Hs[(n+6)*256 + (j ^ (((n+6)&31)<<3))]), m3);
        }
        for (; n < i; n += 2)
          m0 = fmaf(wgt[n], h2f_(Hs[n*256 + (j ^ ((n&31)<<3))]), m0);
        Mp[t] = (m0 + m1) + (m2 + m3);
      }
      __syncthreads();
      if (half == 0) {
        mreg = Mp[j] + Mp[256 + j];
        Mh[j] = f2h(mreg);
      }
      __syncthreads();
    }

    // D: gates — 3 rows/thread, 2-stage register prefetch (r5's verified form)
    float g0 = 0.f, g1 = 0.f, g2 = 0.f;
    {
      const uint4* wr0 = (const uint4*)wb;
      uint4 c0r = wr0[0], c1r = wr0[256], c2r = wr0[512];
#pragma unroll 4
      for (int kb8 = 0; kb8 < 32; ++kb8) {
        uint4 n0 = c0r, n1 = c1r, n2 = c2r;
        if (kb8 < 31) {
          const uint4* wn = (const uint4*)(wb + (size_t)(kb8+1)*12288);
          n0 = wn[0]; n1 = wn[256]; n2 = wn[512];
        }
        const uint4 m8 = *(const uint4*)&Mh[kb8*8];
        g0 = dot8d(c0r, m8, g0);
        g1 = dot8d(c1r, m8, g1);
        g2 = dot8d(c2r, m8, g2);
        c0r = n0; c1r = n1; c2r = n2;
      }
    }

    // E: GRU elementwise, split per half; combine via pbuf
    {
      const int sb = s*1536;
      if (half == 1) {
        // P = gru_cell(M, x): gi = M@pwih^T + pbih (g*), gh = x@pwhh^T + pbhh (GKh)
        const float ghp_r = h2f_(GKh[sb + 768 + j]);
        const float ghp_z = h2f_(GKh[sb + 1024 + j]);
        const float ghp_n = h2f_(GKh[sb + 1280 + j]);
        const float rP = sigm(g0 + eb0 + ghp_r);
        const float zP = sigm(g1 + eb1 + ghp_z);
        const float nP = tanhf(g2 + eb2 + rP * ghp_n);
        pbuf[j] = (1.f - zP) * nP + zP * xj;
      }
      __syncthreads();
      if (half == 0) {
        // C = gru_cell(x, M): gi = x@cwih^T + cbih (GKh), gh = M@cwhh^T + cbhh (g*)
        const float gic_r = h2f_(GKh[sb + j]);
        const float gic_z = h2f_(GKh[sb + 256 + j]);
        const float gic_n = h2f_(GKh[sb + 512 + j]);
        const float rC = sigm(gic_r + g0 + eb0);
        const float zC = sigm(gic_z + g1 + eb1);
        const float nC = tanhf(gic_n + rC * (g2 + eb2));
        const float hval = (1.f - zC) * nC + zC * mreg + pbuf[j];
        H1[((long)i*64 + b)*SD2 + j] = hval;
        const unsigned short hh = f2h(hval);
        Hs[i*256 + (j ^ ((i & 31) << 3))] = hh;   // swizzled LDS
        Hg[(size_t)i*256 + j] = hh;               // linear global (next chunk)
      }
      __syncthreads();
    }
  }
}

__global__ void zero_k(float* p, long n)
{
  for (long idx = (long)blockIdx.x * 256 + threadIdx.x; idx < n; idx += (long)gridDim.x * 256)
    p[idx] = 0.f;
}

// column means of (8192 x 512), grid (8 colblocks, 32 rowslices), atomicAdd
__global__ void colmean_k(const float* __restrict__ X, float* __restrict__ mean)
{
  __shared__ float red[256];
  const int c = blockIdx.x * 64 + (threadIdx.x & 63), rq = threadIdx.x >> 6;
  const int r0 = blockIdx.y * 256;
  float acc = 0.f;
  for (int r = r0 + rq; r < r0 + 256; r += 4) acc += X[(long)r * SD2 + c];
  red[threadIdx.x] = acc;
  __syncthreads();
  if (threadIdx.x < 64) {
    const float s = red[threadIdx.x] + red[64 + threadIdx.x] + red[128 + threadIdx.x] + red[192 + threadIdx.x];
    atomicAdd(&mean[c], s * (1.f / 8192.f));
  }
}

__global__ void rownorm_k(const float* __restrict__ X, const float* __restrict__ mean,
                          float* __restrict__ inv)
{
  const int r = blockIdx.x * 4 + (threadIdx.x >> 6), lane = threadIdx.x & 63;
  const float* xp = X + (long)r * SD2 + lane * 8;
  const float4 v0 = *(const float4*)xp;
  const float4 v1 = *(const float4*)(xp + 4);
  const float4 m0 = *(const float4*)(mean + lane * 8);
  const float4 m1 = *(const float4*)(mean + lane * 8 + 4);
  float ss = 0.f, d;
  d = v0.x - m0.x; ss += d*d;  d = v0.y - m0.y; ss += d*d;
  d = v0.z - m0.z; ss += d*d;  d = v0.w - m0.w; ss += d*d;
  d = v1.x - m1.x; ss += d*d;  d = v1.y - m1.y; ss += d*d;
  d = v1.z - m1.z; ss += d*d;  d = v1.w - m1.w; ss += d*d;
  ss = wsum(ss);
  if (lane == 0) inv[r] = 1.f / (sqrtf(ss) + 1e-6f);
}

// partial G += xhat^T yhat over K slice; grid (8, 8, 16)
__global__ __launch_bounds__(256)
void gpart_k(const float* __restrict__ X, const float* __restrict__ Y,
             const float* __restrict__ mx, const float* __restrict__ my,
             const float* __restrict__ ix, const float* __restrict__ iy,
             float* __restrict__ G)
{
  __shared__ float As[16][68];
  __shared__ float Bs[16][68];
  __shared__ float mxs[64], mys[64];
  const int t = threadIdx.x, tx = t & 15, ty = t >> 4;
  const int ci = blockIdx.y * 64, cj = blockIdx.x * 64;
  if (t < 64) { mxs[t] = mx[ci + t]; mys[t] = my[cj + t]; }
  float acc[4][4];
#pragma unroll
  for (int ii = 0; ii < 4; ++ii)
#pragma unroll
    for (int jj = 0; jj < 4; ++jj) acc[ii][jj] = 0.f;
  const int rl = t >> 4, c4 = (t & 15) * 4;
  __syncthreads();
  const int kend = blockIdx.z * 512 + 512;
  for (int kb = blockIdx.z * 512; kb < kend; kb += 16) {
    const int r = kb + rl;
    const float4 xv = *(const float4*)(X + (long)r * SD2 + ci + c4);
    const float4 yv = *(const float4*)(Y + (long)r * SD2 + cj + c4);
    const float vx = ix[r], vy = iy[r];
    __syncthreads();
    As[rl][c4+0] = (xv.x - mxs[c4+0]) * vx; As[rl][c4+1] = (xv.y - mxs[c4+1]) * vx;
    As[rl][c4+2] = (xv.z - mxs[c4+2]) * vx; As[rl][c4+3] = (xv.w - mxs[c4+3]) * vx;
    Bs[rl][c4+0] = (yv.x - mys[c4+0]) * vy; Bs[rl][c4+1] = (yv.y - mys[c4+1]) * vy;
    Bs[rl][c4+2] = (yv.z - mys[c4+2]) * vy; Bs[rl][c4+3] = (yv.w - mys[c4+3]) * vy;
    __syncthreads();
#pragma unroll
    for (int kk = 0; kk < 16; ++kk) {
      float av[4], bv[4];
      *(float4*)&av[0] = *(const float4*)&As[kk][ty*4];
      *(float4*)&bv[0] = *(const float4*)&Bs[kk][tx*4];
#pragma unroll
      for (int ii = 0; ii < 4; ++ii)
#pragma unroll
        for (int jj = 0; jj < 4; ++jj)
          acc[ii][jj] = fmaf(av[ii], bv[jj], acc[ii][jj]);
    }
  }
#pragma unroll
  for (int ii = 0; ii < 4; ++ii)
#pragma unroll
    for (int jj = 0; jj < 4; ++jj)
      atomicAdd(&G[(long)(ci + ty*4 + ii) * SD2 + cj + tx*4 + jj], acc[ii][jj]);
}

__global__ void sqsum_k(const float* __restrict__ G, float* __restrict__ dl)
{
  __shared__ float red[4];
  float s = 0.f;
  const long base = (long)blockIdx.x * 1024;
#pragma unroll
  for (int it = 0; it < 4; ++it) { const float v = G[base + it*256 + threadIdx.x]; s += v*v; }
  s = wsum(s);
  const int lane = threadIdx.x & 63, wv = threadIdx.x >> 6;
  if (lane == 0) red[wv] = s;
  __syncthreads();
  if (threadIdx.x == 0) atomicAdd(dl, red[0] + red[1] + red[2] + red[3]);
}

// softmax over rows of length 128 (in-place)
__global__ void smax_k(float* __restrict__ S)
{
  const int r = blockIdx.x * 4 + (threadIdx.x >> 6), lane = threadIdx.x & 63;
  float* p = S + (long)r * SN;
  const float v0 = p[lane], v1 = p[lane + 64];
  float mx = fmaxf(v0, v1);
#pragma unroll
  for (int o = 32; o; o >>= 1) mx = fmaxf(mx, __shfl_xor(mx, o));
  const float e0 = expf(v0 - mx), e1 = expf(v1 - mx);
  float s = e0 + e1;
#pragma unroll
  for (int o = 32; o; o >>= 1) s += __shfl_xor(s, o);
  const float inv = 1.f / s;
  p[lane] = e0 * inv; p[lane + 64] = e1 * inv;
}

__global__ void head_k(const float* __restrict__ H, const float* __restrict__ W,
                       const float* __restrict__ bo, float* __restrict__ out)
{
  const int r = blockIdx.x * 4 + (threadIdx.x >> 6), lane = threadIdx.x & 63;
  const float4 h = *(const float4*)(H + (long)r * SD + lane * 4);
#pragma unroll
  for (int c = 0; c < SNC; ++c) {
    const float4 w = *(const float4*)(W + (long)c * SD + lane * 4);
    float p = h.x*w.x + h.y*w.y + h.z*w.z + h.w*w.w;
    p = wsum(p);
    if (lane == 0) out[(long)r * SNC + c] = p + bo[c];
  }
}

__global__ void fin_k(const float* __restrict__ dl, float* __restrict__ out)
{
  out[0] = (dl[0] + dl[1]) * (0.3f / (512.f * 512.f));
}

// ---------------------------------------------------------------------------
extern "C" void kernel_launch(void* const* d_in, const int* in_sizes, int n_in,
                              void* d_out, int out_size, void* d_ws, size_t ws_size,
                              hipStream_t stream)
{
  (void)in_sizes; (void)n_in; (void)out_size; (void)ws_size;

  static bool attr_set = false;
  if (!attr_set) {
    hipFuncSetAttribute(reinterpret_cast<const void*>(step_chunk_k),
                        hipFuncAttributeMaxDynamicSharedMemorySize, SMEM_BYTES);
    attr_set = true;
  }

  const float* F    = (const float*)d_in[0];
  const int*   adj1 = (const int*)  d_in[1];
  const int*   adj2 = (const int*)  d_in[2];
  const float* fc1w = (const float*)d_in[6];
  const float* fc1b = (const float*)d_in[7];
  const float *g_wih[4], *g_whh[4], *g_bih[4], *g_bhh[4];  // gcs, gps, gcl, gpl
  for (int g = 0; g < 4; ++g) {
    g_wih[g] = (const float*)d_in[8 + g*4 + 0];
    g_whh[g] = (const float*)d_in[8 + g*4 + 1];
    g_bih[g] = (const float*)d_in[8 + g*4 + 2];
    g_bhh[g] = (const float*)d_in[8 + g*4 + 3];
  }
  const float* gat_wq[2] = {(const float*)d_in[24], (const float*)d_in[28]};
  const float* gat_bq[2] = {(const float*)d_in[25], (const float*)d_in[29]};
  const float* gat_wk[2] = {(const float*)d_in[26], (const float*)d_in[30]};
  const float* gat_bk[2] = {(const float*)d_in[27], (const float*)d_in[31]};
  const float* aff1 = (const float*)d_in[32];
  const float* aff2 = (const float*)d_in[33];
  const float* mw1  = (const float*)d_in[34];
  const float* mb1  = (const float*)d_in[35];
  const float* mw2  = (const float*)d_in[36];
  const float* mb2  = (const float*)d_in[37];
  const float* ow   = (const float*)d_in[38];
  const float* ob   = (const float*)d_in[39];
  float* out = (float*)d_out;

  // ---- workspace layout ----
  float* ws = (float*)d_ws;
  size_t off = 0;
  auto take = [&](size_t nf){ float* p = ws + off; off += nf; return p; };
  float* region = take(22552576);           // overlay region
  float* X0f  = region;                     // 2,097,152 (time-major layer-0 fwd)
  float* X0r  = region + 2097152;           // 2,097,152 (time-major layer-0 bwd)
  float* Qtb  = region + 4194304;           // 4 x 2,097,152
  float* Qtmp = region + 12582912;          // 2,097,152
  float* Htmp = region + 14680064;          // b-major H0 temp (early only)
  // finals overlay (sequential-phase buffers dead by then)
  float* T  = region;                       // 4,194,304
  float* Sb = region + 4194304;             // 1,048,576
  float* HH = region + 5242880;             // 4,194,304
  float* h1 = region + 9437184;             // 2,097,152
  float* h2 = region + 11534336;            // 2,097,152
  float* Ocat[2][2];                        // time-major H1 storage, stride 512
  for (int c = 0; c < 2; ++c) for (int l = 0; l < 2; ++l) Ocat[c][l] = take(4194304);
  float* S0b   = take(32768);               // 4 x 8192
  unsigned short* WtB  = (unsigned short*)take(786432);  // fp16 [cd][32][1536][8]
  unsigned short* WgkB = (unsigned short*)take(786432);  // fp16 [cd][32][1536][8]
  unsigned short* HhB  = (unsigned short*)take(4194304); // fp16 shadow [256][128][256]
  float* meanx = take(512);
  float* meany = take(512);
  float* invx  = take(8192);
  float* invy  = take(8192);
  float* dl    = take(8);
  float* Gbuf  = take(262144);

  // H0 = relu(F @ fc1w^T + fc1b)  (b-major temp), then spread to time-major
  gemm_k<false,true,true,false><<<dim3(4,64,1),256,0,stream>>>(
      F, fc1w, fc1b, Htmp, SD, SE, SE, SE, SD, 0,0,0);
  spread_k<<<SBN,256,0,stream>>>(Htmp, X0f, X0r);

  for (int l = 0; l < 2; ++l) {
    PTArgs pt, pg; StepArgs sta;
    sta.ldX = l ? SD2 : SD;
    sta.Wt = WtB; sta.Wgk = WgkB; sta.Hh = HhB;
    const int ldX = sta.ldX;
    for (int cd = 0; cd < 4; ++cd) {
      const int ch = cd >> 1;  // 0 = s-channel, 1 = l-channel
      const float* X = (l == 0) ? ((cd & 1) ? X0r : X0f)
                                : (Ocat[ch][0] + (cd & 1) * SD);
      const float* wq   = gat_wq[ch] + l * SD * SD;
      const float* bq   = gat_bq[ch] + l * SD;
      const float* wk   = gat_wk[ch] + l * SD * SD;
      const float* bk   = gat_bk[ch] + l * SD;
      const float* cwih = g_wih[ch*2+0] + l * SD3 * SD;
      const float* cwhh = g_whh[ch*2+0] + l * SD3 * SD;
      const float* cbih = g_bih[ch*2+0] + l * SD3;
      const float* cbhh = g_bhh[ch*2+0] + l * SD3;
      const float* pwih = g_wih[ch*2+1] + l * SD3 * SD;
      const float* pwhh = g_whh[ch*2+1] + l * SD3 * SD;
      const float* pbih = g_bih[ch*2+1] + l * SD3;
      const float* pbhh = g_bhh[ch*2+1] + l * SD3;
      pt.wc[cd] = cwhh; pt.wp[cd] = pwih;   // step-gate weights
      pg.wc[cd] = cwih; pg.wp[cd] = pwhh;   // GK weights
      // Qtmp = X@wq^T + bq ; Qt = Qtmp@wk ; S0 = Qtmp . bk
      gemm_k<false,true,false,false><<<dim3(4,64,1),256,0,stream>>>(
          X, wq, bq, Qtmp, SD, SD, ldX, SD, SD, 0,0,0);
      gemm_k<true,false,false,false><<<dim3(4,64,1),256,0,stream>>>(
          Qtmp, wk, nullptr, Qtb + (size_t)cd*2097152, SD, SD, SD, SD, SD, 0,0,0);
      s0_k<<<SBN/4,256,0,stream>>>(Qtmp, bk, S0b + cd*SBN);
      float* H1mut = Ocat[ch][l] + (cd & 1) * SD;
      sta.Qt[cd] = Qtb + (size_t)cd*2097152;
      sta.S0[cd] = S0b + cd*SBN;
      sta.H1[cd] = H1mut;
      sta.adj[cd] = ch ? adj2 : adj1; sta.rev[cd] = cd & 1;
      sta.bc[cd]  = cbhh; sta.bp[cd]  = pbih;
      sta.bgc[cd] = cbih; sta.bgp[cd] = pbhh;
      sta.X[cd] = X;
    }
    pt.Wt = WtB;  packT_k<<<dim3(32,4),256,0,stream>>>(pt);
    pg.Wt = WgkB; packT_k<<<dim3(32,4),256,0,stream>>>(pg);

    for (int s0 = 0; s0 < SN; s0 += CS) {
      sta.s0 = s0;
      step_chunk_k<<<256,512,SMEM_BYTES,stream>>>(sta);
    }
  }

  // diff loss (row-permutation invariant -> time-major OK)
  zero_k<<<1,256,0,stream>>>(dl, 2);
  for (int l = 0; l < 2; ++l) {
    zero_k<<<4,256,0,stream>>>(meanx, 1024);  // meanx+meany contiguous
    colmean_k<<<dim3(8,32,1),256,0,stream>>>(Ocat[0][l], meanx);
    colmean_k<<<dim3(8,32,1),256,0,stream>>>(Ocat[1][l], meany);
    rownorm_k<<<SBN/4,256,0,stream>>>(Ocat[0][l], meanx, invx);
    rownorm_k<<<SBN/4,256,0,stream>>>(Ocat[1][l], meany, invy);
    zero_k<<<256,256,0,stream>>>(Gbuf, (long)SD2*SD2);
    gpart_k<<<dim3(8,8,16),256,0,stream>>>(Ocat[0][l], Ocat[1][l], meanx, meany, invx, invy, Gbuf);
    sqsum_k<<<256,256,0,stream>>>(Gbuf, dl + l);
  }

  // cross attention + final MLP (h1 accumulated from F / HSn / HLn slices)
  gemm_k<true,false,false,false><<<dim3(8,64,1),256,0,stream>>>(
      Ocat[0][1], aff1, nullptr, T, SD2, SD2, SD2, SD2, SD2, 0,0,0);
  gemm_k<false,false,false,false><<<dim3(2,1,64),256,0,stream>>>(
      T, Ocat[1][1], nullptr, Sb, SN, SD2, 64*SD2, 64*SD2, SN, SD2, SD2, (long)SN*SN);
  smax_k<<<SBN/4,256,0,stream>>>(Sb);
  gemm_k<true,false,false,false><<<dim3(8,1,64),256,0,stream>>>(
      Sb, Ocat[1][1], nullptr, HH, SD2, SN, SN, 64*SD2, SD2, (long)SN*SN, SD2, (long)SN*SD2);
  gemm_k<false,true,false,false><<<dim3(4,64,1),256,0,stream>>>(
      F, mw1, mb1, h1, SD, SE, SE, SIN, SD, 0,0,0);
  gemm_k<false,false,false,true><<<dim3(4,64,1),256,0,stream>>>(
      HH, mw1 + 1024, nullptr, h1, SD, SD2, SD2, SIN, SD, 0,0,0);
  gemm_k<true,false,false,false><<<dim3(8,64,1),256,0,stream>>>(
      Ocat[1][1], aff2, nullptr, T, SD2, SD2, SD2, SD2, SD2, 0,0,0);
  gemm_k<false,false,false,false><<<dim3(2,1,64),256,0,stream>>>(
      T, Ocat[0][1], nullptr, Sb, SN, SD2, 64*SD2, 64*SD2, SN, SD2, SD2, (long)SN*SN);
  smax_k<<<SBN/4,256,0,stream>>>(Sb);
  gemm_k<true,false,false,false><<<dim3(8,1,64),256,0,stream>>>(
      Sb, Ocat[0][1], nullptr, HH, SD2, SN, SN, 64*SD2, SD2, (long)SN*SN, SD2, (long)SN*SD2);
  gemm_k<false,false,true,true><<<dim3(4,64,1),256,0,stream>>>(
      HH, mw1 + 1536, nullptr, h1, SD, SD2, SD2, SIN, SD, 0,0,0);
  gemm_k<false,true,true,false><<<dim3(4,64,1),256,0,stream>>>(
      h1, mw2, mb2, h2, SD, SD, SD, SD, SD, 0,0,0);
  head_k<<<SBN/4,256,0,stream>>>(h2, ow, ob, out);
  fin_k<<<1,1,0,stream>>>(dl, out + SBN * SNC);
}